// Round 2
// baseline (2225.379 us; speedup 1.0000x reference)
//
#include <hip/hip_runtime.h>
#include <cstdint>
#include <cstddef>

// ---------------------------------------------------------------------------
// GAT forward: N=30000, E=480000 (+N self loops), ATOM=HID=128, H=4, OUT=256
// All fp32. Outputs: probs [64,2] then alpha2 [E+N, 4], flat in d_out.
// ---------------------------------------------------------------------------

__device__ __forceinline__ float lrelu(float v) { return v >= 0.f ? v : 0.2f * v; }

// float atomic max via signed/unsigned int compare trick.
// Init bit pattern must be -inf (0xFF800000) or 0xFFFFFFFF.
__device__ __forceinline__ void atomicMaxF(float* addr, float v) {
    if (v >= 0.f) atomicMax((int*)addr, __float_as_int(v));
    else          atomicMin((unsigned int*)addr, __float_as_uint(v));
}

__global__ void fill_f32(float* p, float v, int n) {
    int i = blockIdx.x * blockDim.x + threadIdx.x;
    if (i < n) p[i] = v;
}

// ---------------------------------------------------------------------------
// C[M,512] = A[M,128] @ B[128,512].  64x64 tile, 256 threads, 4x4 per thread.
// As [64][132]: full K=128 width + 4-float pad (16B-aligned rows, no alias).
// ---------------------------------------------------------------------------
__global__ __launch_bounds__(256) void gemm128(const float* __restrict__ A,
                                               const float* __restrict__ B,
                                               float* __restrict__ C, int M, int N) {
    __shared__ float As[64][132];
    __shared__ float Bs[128][64];
    const int tid  = threadIdx.x;
    const int row0 = blockIdx.x * 64, col0 = blockIdx.y * 64;

#pragma unroll
    for (int i = 0; i < 8; i++) {                // A tile: 64 rows x 128 cols
        int idx = tid + i * 256;
        int r = idx >> 5, c4 = idx & 31;
        int gr = row0 + r;
        float4 v = make_float4(0.f, 0.f, 0.f, 0.f);
        if (gr < M) v = *(const float4*)&A[(size_t)gr * 128 + c4 * 4];
        *(float4*)&As[r][c4 * 4] = v;
    }
#pragma unroll
    for (int i = 0; i < 8; i++) {                // B tile: 128 rows x 64 cols
        int idx = tid + i * 256;
        int r = idx >> 4, c4 = idx & 15;
        *(float4*)&Bs[r][c4 * 4] = *(const float4*)&B[(size_t)r * N + col0 + c4 * 4];
    }
    __syncthreads();

    const int tx = tid & 15, ty = tid >> 4;
    float acc[4][4] = {};
#pragma unroll 2
    for (int k = 0; k < 128; k += 4) {
        float4 a[4], b[4];
#pragma unroll
        for (int i = 0; i < 4; i++) a[i] = *(const float4*)&As[ty * 4 + i][k];
#pragma unroll
        for (int j = 0; j < 4; j++) b[j] = *(const float4*)&Bs[k + j][tx * 4];
#pragma unroll
        for (int i = 0; i < 4; i++) {
            acc[i][0] += a[i].x * b[0].x + a[i].y * b[1].x + a[i].z * b[2].x + a[i].w * b[3].x;
            acc[i][1] += a[i].x * b[0].y + a[i].y * b[1].y + a[i].z * b[2].y + a[i].w * b[3].y;
            acc[i][2] += a[i].x * b[0].z + a[i].y * b[1].z + a[i].z * b[2].z + a[i].w * b[3].z;
            acc[i][3] += a[i].x * b[0].w + a[i].y * b[1].w + a[i].z * b[2].w + a[i].w * b[3].w;
        }
    }
#pragma unroll
    for (int i = 0; i < 4; i++) {
        int gr = row0 + ty * 4 + i;
        if (gr < M)
            *(float4*)&C[(size_t)gr * N + col0 + tx * 4] =
                make_float4(acc[i][0], acc[i][1], acc[i][2], acc[i][3]);
    }
}

// ---------------------------------------------------------------------------
// Per-node, per-head attention scores: s_src[n,h] = sum_c h[n,h,c]*a_s[h,c]
// One wave per (node, head): block 256 = 4 waves = 4 heads, grid = N.
// ---------------------------------------------------------------------------
__global__ __launch_bounds__(256) void heads_dot(const float* __restrict__ h,
                                                 const float* __restrict__ a_s,
                                                 const float* __restrict__ a_d,
                                                 float* __restrict__ ssrc,
                                                 float* __restrict__ sdst) {
    int n = blockIdx.x;
    int hh = threadIdx.x >> 6, l = threadIdx.x & 63;
    const float* row = h + (size_t)n * 512 + hh * 128;
    float x0 = row[l], x1 = row[l + 64];
    float s0 = x0 * a_s[hh * 128 + l] + x1 * a_s[hh * 128 + l + 64];
    float d0 = x0 * a_d[hh * 128 + l] + x1 * a_d[hh * 128 + l + 64];
    for (int o = 32; o; o >>= 1) { s0 += __shfl_down(s0, o); d0 += __shfl_down(d0, o); }
    if (l == 0) { ssrc[n * 4 + hh] = s0; sdst[n * 4 + hh] = d0; }
}

// ---------------------------------------------------------------------------
// Edge passes. Thread per edge; heads vectorized as float4.
// ---------------------------------------------------------------------------
__global__ void edge_max(const int* __restrict__ ei, int E, int ET,
                         const float4* __restrict__ ssrc, const float4* __restrict__ sdst,
                         float* __restrict__ m) {
    int e = blockIdx.x * 256 + threadIdx.x;
    if (e >= ET) return;
    int s, d;
    if (e < E) { s = ei[e]; d = ei[E + e]; } else { s = d = e - E; }
    float4 a = ssrc[s], b = sdst[d];
    atomicMaxF(m + d * 4 + 0, lrelu(a.x + b.x));
    atomicMaxF(m + d * 4 + 1, lrelu(a.y + b.y));
    atomicMaxF(m + d * 4 + 2, lrelu(a.z + b.z));
    atomicMaxF(m + d * 4 + 3, lrelu(a.w + b.w));
}

__global__ void edge_den(const int* __restrict__ ei, int E, int ET,
                         const float4* __restrict__ ssrc, const float4* __restrict__ sdst,
                         const float4* __restrict__ m4, float* __restrict__ den) {
    int e = blockIdx.x * 256 + threadIdx.x;
    if (e >= ET) return;
    int s, d;
    if (e < E) { s = ei[e]; d = ei[E + e]; } else { s = d = e - E; }
    float4 a = ssrc[s], b = sdst[d];
    float4 mm = m4[d];
    atomicAdd(den + d * 4 + 0, __expf(lrelu(a.x + b.x) - mm.x));
    atomicAdd(den + d * 4 + 1, __expf(lrelu(a.y + b.y) - mm.y));
    atomicAdd(den + d * 4 + 2, __expf(lrelu(a.z + b.z) - mm.z));
    atomicAdd(den + d * 4 + 3, __expf(lrelu(a.w + b.w) - mm.w));
}

__global__ void alpha_out(const int* __restrict__ ei, int E, int ET,
                          const float4* __restrict__ ssrc, const float4* __restrict__ sdst,
                          const float4* __restrict__ m4, const float4* __restrict__ den4,
                          float4* __restrict__ aout) {
    int e = blockIdx.x * 256 + threadIdx.x;
    if (e >= ET) return;
    int s, d;
    if (e < E) { s = ei[e]; d = ei[E + e]; } else { s = d = e - E; }
    float4 a = ssrc[s], b = sdst[d];
    float4 mm = m4[d], dd = den4[d];
    float4 r;
    r.x = __expf(lrelu(a.x + b.x) - mm.x) / dd.x;
    r.y = __expf(lrelu(a.y + b.y) - mm.y) / dd.y;
    r.z = __expf(lrelu(a.z + b.z) - mm.z) / dd.z;
    r.w = __expf(lrelu(a.w + b.w) - mm.w) / dd.w;
    aout[e] = r;
}

// Layer-1 aggregate: head-MEAN. Block=512 (h=t>>7,c=t&127); LDS-reduce the 4
// heads so only 128 atomics/edge hit out1[N,128].
__global__ __launch_bounds__(512) void scatter1(const int* __restrict__ ei, int E, int ET,
                                                const float* __restrict__ h1,
                                                const float* __restrict__ ssrc,
                                                const float* __restrict__ sdst,
                                                const float* __restrict__ m,
                                                const float* __restrict__ den,
                                                float* __restrict__ out1) {
    __shared__ float buf[512];
    int t = threadIdx.x, h = t >> 7;
    for (int e = blockIdx.x; e < ET; e += gridDim.x) {
        int s, d;
        if (e < E) { s = ei[e]; d = ei[E + e]; } else { s = d = e - E; }
        float ev = lrelu(ssrc[s * 4 + h] + sdst[d * 4 + h]);
        float alpha = __expf(ev - m[d * 4 + h]) / den[d * 4 + h];
        buf[t] = h1[(size_t)s * 512 + t] * alpha;
        __syncthreads();
        if (t < 128)
            atomicAdd(&out1[(size_t)d * 128 + t],
                      0.25f * (buf[t] + buf[t + 128] + buf[t + 256] + buf[t + 384]));
        __syncthreads();
    }
}

// Layer-2 aggregate: concat. 512 atomics/edge into out2[N,512].
__global__ __launch_bounds__(512) void scatter2(const int* __restrict__ ei, int E, int ET,
                                                const float* __restrict__ h2,
                                                const float* __restrict__ aout,
                                                float* __restrict__ out2) {
    int t = threadIdx.x, h = t >> 7;
    for (int e = blockIdx.x; e < ET; e += gridDim.x) {
        int s, d;
        if (e < E) { s = ei[e]; d = ei[E + e]; } else { s = d = e - E; }
        float alpha = aout[(size_t)e * 4 + h];
        atomicAdd(&out2[(size_t)d * 512 + t], h2[(size_t)s * 512 + t] * alpha);
    }
}

// x = lrelu(LN(x + b1)) per node row of 128; one wave per node.
__global__ __launch_bounds__(256) void ln_lrelu(float* __restrict__ hbuf,
                                                const float* __restrict__ b1,
                                                const float* __restrict__ gg,
                                                const float* __restrict__ bb, int Nn) {
    int w = threadIdx.x >> 6, l = threadIdx.x & 63;
    int n = blockIdx.x * 4 + w;
    if (n >= Nn) return;
    float* row = hbuf + (size_t)n * 128;
    float x0 = row[l] + b1[l], x1 = row[l + 64] + b1[l + 64];
    float s = x0 + x1;
    for (int o = 32; o; o >>= 1) s += __shfl_down(s, o);
    s = __shfl(s, 0);
    float mu = s * (1.f / 128.f);
    float d0 = x0 - mu, d1 = x1 - mu;
    float v = d0 * d0 + d1 * d1;
    for (int o = 32; o; o >>= 1) v += __shfl_down(v, o);
    v = __shfl(v, 0);
    float r = rsqrtf(v * (1.f / 128.f) + 1e-5f);
    float y0 = gg[l] * d0 * r + bb[l];
    float y1 = gg[l + 64] * d1 * r + bb[l + 64];
    row[l]      = lrelu(y0);
    row[l + 64] = lrelu(y1);
}

// pooled[g,c] += sum over nodes of lrelu(out2[n,c]+b2[c]); batch sorted, so
// accumulate locally and flush on graph change (few atomics per block).
__global__ __launch_bounds__(512) void pool_k(const float* __restrict__ out2,
                                              const float* __restrict__ b2,
                                              const int* __restrict__ batch,
                                              float* __restrict__ pooled, int Nn) {
    int c = threadIdx.x;
    int n0 = blockIdx.x * 64, n1 = min(n0 + 64, Nn);
    if (n0 >= Nn) return;
    float bc = b2[c];
    int g = batch[n0];
    float acc = 0.f;
    for (int n = n0; n < n1; ++n) {
        int bg = batch[n];
        if (bg != g) { atomicAdd(&pooled[g * 512 + c], acc); acc = 0.f; g = bg; }
        float v = out2[(size_t)n * 512 + c] + bc;
        acc += lrelu(v);
    }
    atomicAdd(&pooled[g * 512 + c], acc);
}

__global__ void count_k(const int* __restrict__ batch, float* __restrict__ cnt, int Nn) {
    int i = blockIdx.x * blockDim.x + threadIdx.x;
    if (i < Nn) atomicAdd(&cnt[batch[i]], 1.f);
}

// ---------------------------------------------------------------------------
// MLP head (G=64 rows). Block reductions for LN.
// ---------------------------------------------------------------------------
__device__ __forceinline__ float block_sum(float v, volatile float* sbuf, int tid, int nw) {
    for (int o = 32; o; o >>= 1) v += __shfl_down(v, o);
    if ((tid & 63) == 0) sbuf[tid >> 6] = v;
    __syncthreads();
    if (tid == 0) { float r = 0.f; for (int i = 0; i < nw; i++) r += sbuf[i]; sbuf[0] = r; }
    __syncthreads();
    float r = sbuf[0];
    __syncthreads();
    return r;
}

__global__ __launch_bounds__(128) void lin0_k(const float* __restrict__ pooled,
                                              const float* __restrict__ cnt,
                                              const float* __restrict__ W,
                                              const float* __restrict__ b,
                                              float* __restrict__ z0) {
    int g = blockIdx.x, j = threadIdx.x;
    float inv = 1.f / fmaxf(cnt[g], 1.f);
    float acc = 0.f;
    for (int k = 0; k < 512; k++) acc += pooled[g * 512 + k] * W[k * 128 + j];
    z0[g * 128 + j] = acc * inv + b[j];
}

__global__ __launch_bounds__(256) void lin1_k(const float* __restrict__ z0,
                                              const float* __restrict__ W,
                                              const float* __restrict__ b,
                                              const float* __restrict__ gw,
                                              const float* __restrict__ gb,
                                              float* __restrict__ z1) {
    __shared__ float sbuf[8];
    int g = blockIdx.x, j = threadIdx.x;
    float acc = b[j];
    for (int k = 0; k < 128; k++) acc += z0[g * 128 + k] * W[k * 256 + j];
    float mu = block_sum(acc, sbuf, j, 4) * (1.f / 256.f);
    float d = acc - mu;
    float var = block_sum(d * d, sbuf, j, 4) * (1.f / 256.f);
    float y = gw[j] * d * rsqrtf(var + 1e-5f) + gb[j];
    z1[g * 256 + j] = fmaxf(y, 0.f);
}

__global__ __launch_bounds__(128) void lin2_k(const float* __restrict__ z1,
                                              const float* __restrict__ W,
                                              const float* __restrict__ b,
                                              const float* __restrict__ gw,
                                              const float* __restrict__ gb,
                                              float* __restrict__ z2) {
    __shared__ float sbuf[8];
    int g = blockIdx.x, j = threadIdx.x;
    float acc = b[j];
    for (int k = 0; k < 256; k++) acc += z1[g * 256 + k] * W[k * 128 + j];
    float mu = block_sum(acc, sbuf, j, 2) * (1.f / 128.f);
    float d = acc - mu;
    float var = block_sum(d * d, sbuf, j, 2) * (1.f / 128.f);
    float y = gw[j] * d * rsqrtf(var + 1e-5f) + gb[j];
    z2[g * 128 + j] = fmaxf(y, 0.f);
}

__global__ __launch_bounds__(64) void lin3_k(const float* __restrict__ z2,
                                             const float* __restrict__ W,
                                             const float* __restrict__ b,
                                             float* __restrict__ probs) {
    int g = blockIdx.x, l = threadIdx.x;
    float p0 = 0.f, p1 = 0.f;
    for (int k = l; k < 128; k += 64) {
        float z = z2[g * 128 + k];
        p0 += z * W[k * 2 + 0];
        p1 += z * W[k * 2 + 1];
    }
    for (int o = 32; o; o >>= 1) { p0 += __shfl_down(p0, o); p1 += __shfl_down(p1, o); }
    if (l == 0) {
        p0 += b[0]; p1 += b[1];
        float mx = fmaxf(p0, p1);
        float e0 = __expf(p0 - mx), e1 = __expf(p1 - mx);
        float s = e0 + e1;
        probs[g * 2 + 0] = e0 / s;
        probs[g * 2 + 1] = e1 / s;
    }
}

// ---------------------------------------------------------------------------
extern "C" void kernel_launch(void* const* d_in, const int* in_sizes, int n_in,
                              void* d_out, int out_size, void* d_ws, size_t ws_size,
                              hipStream_t stream) {
    const float* x    = (const float*)d_in[0];
    const int*   ei   = (const int*)d_in[1];
    const int*   batch= (const int*)d_in[2];
    const float* W1   = (const float*)d_in[3];
    const float* as1  = (const float*)d_in[4];
    const float* ad1  = (const float*)d_in[5];
    const float* b1   = (const float*)d_in[6];
    const float* g_ln = (const float*)d_in[7];
    const float* b_ln = (const float*)d_in[8];
    const float* W2   = (const float*)d_in[9];
    const float* as2  = (const float*)d_in[10];
    const float* ad2  = (const float*)d_in[11];
    const float* b2   = (const float*)d_in[12];
    const float* Wl0  = (const float*)d_in[13];
    const float* bl0  = (const float*)d_in[14];
    const float* Ws1  = (const float*)d_in[15];
    const float* bs1  = (const float*)d_in[16];
    const float* g1   = (const float*)d_in[17];
    const float* bb1  = (const float*)d_in[18];
    const float* Ws2  = (const float*)d_in[19];
    const float* bs2  = (const float*)d_in[20];
    const float* g2   = (const float*)d_in[21];
    const float* bb2  = (const float*)d_in[22];
    const float* Ws3  = (const float*)d_in[23];
    const float* bs3  = (const float*)d_in[24];
    (void)n_in; (void)out_size; (void)ws_size;

    const int Nn = in_sizes[0] / 128;   // 30000
    const int E  = in_sizes[1] / 2;     // 480000
    const int ET = E + Nn;              // 510000
    const int G  = 64;

    // ---- workspace layout (all sizes multiples of 256 B) ----
    char* ws = (char*)d_ws;
    size_t off = 0;
    auto alloc = [&](size_t bytes) { void* p = ws + off; off += (bytes + 255) & ~(size_t)255; return p; };
    float* h_a    = (float*)alloc((size_t)Nn * 512 * 4);   // h1, later h2
    float* hln    = (float*)alloc((size_t)Nn * 128 * 4);   // out1 -> LN in place
    float* out2   = (float*)alloc((size_t)Nn * 512 * 4);
    float* den1   = (float*)alloc((size_t)Nn * 4 * 4);
    float* den2   = (float*)alloc((size_t)Nn * 4 * 4);
    float* pooled = (float*)alloc((size_t)G * 512 * 4);
    float* cnt    = (float*)alloc((size_t)G * 4);
    float* z0     = (float*)alloc((size_t)G * 128 * 4);
    float* z1     = (float*)alloc((size_t)G * 256 * 4);
    float* z2     = (float*)alloc((size_t)G * 128 * 4);
    float* m1     = (float*)alloc((size_t)Nn * 4 * 4);
    float* m2     = (float*)alloc((size_t)Nn * 4 * 4);
    float* ssrc   = (float*)alloc((size_t)Nn * 4 * 4);
    float* sdst   = (float*)alloc((size_t)Nn * 4 * 4);

    float* probs = (float*)d_out;
    float* aout  = (float*)d_out + 128;   // alpha [ET,4]

    // ---- init (ws is poisoned 0xAA every call) ----
    // hln + out2 are contiguous; den1..cnt are contiguous.
    hipMemsetAsync(hln, 0, (size_t)Nn * 128 * 4 + (size_t)Nn * 512 * 4, stream);
    hipMemsetAsync(den1, 0, (size_t)Nn * 4 * 4 * 2 + (size_t)G * 512 * 4 + (size_t)G * 4, stream);
    fill_f32<<<(Nn * 8 + 255) / 256, 256, 0, stream>>>(m1, -__builtin_huge_valf(), Nn * 8); // m1+m2

    dim3 ggrid((Nn + 63) / 64, 8);
    const int eblks = (ET + 255) / 256;

    // ---- layer 1 ----
    gemm128<<<ggrid, 256, 0, stream>>>(x, W1, h_a, Nn, 512);
    heads_dot<<<Nn, 256, 0, stream>>>(h_a, as1, ad1, ssrc, sdst);
    edge_max<<<eblks, 256, 0, stream>>>(ei, E, ET, (const float4*)ssrc, (const float4*)sdst, m1);
    edge_den<<<eblks, 256, 0, stream>>>(ei, E, ET, (const float4*)ssrc, (const float4*)sdst,
                                        (const float4*)m1, den1);
    scatter1<<<2048, 512, 0, stream>>>(ei, E, ET, h_a, ssrc, sdst, m1, den1, hln);
    ln_lrelu<<<(Nn + 3) / 4, 256, 0, stream>>>(hln, b1, g_ln, b_ln, Nn);

    // ---- layer 2 ----
    gemm128<<<ggrid, 256, 0, stream>>>(hln, W2, h_a, Nn, 512);
    heads_dot<<<Nn, 256, 0, stream>>>(h_a, as2, ad2, ssrc, sdst);
    edge_max<<<eblks, 256, 0, stream>>>(ei, E, ET, (const float4*)ssrc, (const float4*)sdst, m2);
    edge_den<<<eblks, 256, 0, stream>>>(ei, E, ET, (const float4*)ssrc, (const float4*)sdst,
                                        (const float4*)m2, den2);
    alpha_out<<<eblks, 256, 0, stream>>>(ei, E, ET, (const float4*)ssrc, (const float4*)sdst,
                                         (const float4*)m2, (const float4*)den2, (float4*)aout);
    scatter2<<<2048, 512, 0, stream>>>(ei, E, ET, h_a, aout, out2);

    // ---- pool + MLP head ----
    pool_k<<<(Nn + 63) / 64, 512, 0, stream>>>(out2, b2, batch, pooled, Nn);
    count_k<<<(Nn + 255) / 256, 256, 0, stream>>>(batch, cnt, Nn);
    lin0_k<<<G, 128, 0, stream>>>(pooled, cnt, Wl0, bl0, z0);
    lin1_k<<<G, 256, 0, stream>>>(z0, Ws1, bs1, g1, bb1, z1);
    lin2_k<<<G, 128, 0, stream>>>(z1, Ws2, bs2, g2, bb2, z2);
    lin3_k<<<G, 64, 0, stream>>>(z2, Ws3, bs3, probs);
}

// Round 7
// 976.701 us; speedup vs baseline: 2.2785x; 2.2785x over previous
//
#include <hip/hip_runtime.h>
#include <cstdint>
#include <cstddef>

// ---------------------------------------------------------------------------
// GAT forward: N=30000, E=480000 (+N self loops), ATOM=HID=128, H=4, OUT=256
// All fp32. Outputs: probs [64,2] then alpha2 [E+N, 4], flat in d_out.
// Round 2: CSR-by-destination + per-wave softmax/aggregate (no edge atomics).
// Rounds 3-6: identical resubmits (broker acquisition timeouts; never measured).
// ---------------------------------------------------------------------------

__device__ __forceinline__ float lrelu(float v) { return v >= 0.f ? v : 0.2f * v; }

__device__ __forceinline__ float4 lrelu4(float4 v) {
    return make_float4(lrelu(v.x), lrelu(v.y), lrelu(v.z), lrelu(v.w));
}
__device__ __forceinline__ float4 add4(float4 a, float4 b) {
    return make_float4(a.x + b.x, a.y + b.y, a.z + b.z, a.w + b.w);
}

// ---------------------------------------------------------------------------
// C[M,512] = A[M,128] @ B[128,512].  64x64 tile, 256 threads, 4x4 per thread.
// ---------------------------------------------------------------------------
__global__ __launch_bounds__(256) void gemm128(const float* __restrict__ A,
                                               const float* __restrict__ B,
                                               float* __restrict__ C, int M, int N) {
    __shared__ float As[64][132];
    __shared__ float Bs[128][64];
    const int tid  = threadIdx.x;
    const int row0 = blockIdx.x * 64, col0 = blockIdx.y * 64;

#pragma unroll
    for (int i = 0; i < 8; i++) {                // A tile: 64 rows x 128 cols
        int idx = tid + i * 256;
        int r = idx >> 5, c4 = idx & 31;
        int gr = row0 + r;
        float4 v = make_float4(0.f, 0.f, 0.f, 0.f);
        if (gr < M) v = *(const float4*)&A[(size_t)gr * 128 + c4 * 4];
        *(float4*)&As[r][c4 * 4] = v;
    }
#pragma unroll
    for (int i = 0; i < 8; i++) {                // B tile: 128 rows x 64 cols
        int idx = tid + i * 256;
        int r = idx >> 4, c4 = idx & 15;
        *(float4*)&Bs[r][c4 * 4] = *(const float4*)&B[(size_t)r * N + col0 + c4 * 4];
    }
    __syncthreads();

    const int tx = tid & 15, ty = tid >> 4;
    float acc[4][4] = {};
#pragma unroll 2
    for (int k = 0; k < 128; k += 4) {
        float4 a[4], b[4];
#pragma unroll
        for (int i = 0; i < 4; i++) a[i] = *(const float4*)&As[ty * 4 + i][k];
#pragma unroll
        for (int j = 0; j < 4; j++) b[j] = *(const float4*)&Bs[k + j][tx * 4];
#pragma unroll
        for (int i = 0; i < 4; i++) {
            acc[i][0] += a[i].x * b[0].x + a[i].y * b[1].x + a[i].z * b[2].x + a[i].w * b[3].x;
            acc[i][1] += a[i].x * b[0].y + a[i].y * b[1].y + a[i].z * b[2].y + a[i].w * b[3].y;
            acc[i][2] += a[i].x * b[0].z + a[i].y * b[1].z + a[i].z * b[2].z + a[i].w * b[3].z;
            acc[i][3] += a[i].x * b[0].w + a[i].y * b[1].w + a[i].z * b[2].w + a[i].w * b[3].w;
        }
    }
#pragma unroll
    for (int i = 0; i < 4; i++) {
        int gr = row0 + ty * 4 + i;
        if (gr < M)
            *(float4*)&C[(size_t)gr * N + col0 + tx * 4] =
                make_float4(acc[i][0], acc[i][1], acc[i][2], acc[i][3]);
    }
}

// ---------------------------------------------------------------------------
// Per-node, per-head scores: ssrc[n,h] = sum_c h[n,h,c]*a_s[h,c]; same for sdst.
// ---------------------------------------------------------------------------
__global__ __launch_bounds__(256) void heads_dot(const float* __restrict__ h,
                                                 const float* __restrict__ a_s,
                                                 const float* __restrict__ a_d,
                                                 float* __restrict__ ssrc,
                                                 float* __restrict__ sdst) {
    int n = blockIdx.x;
    int hh = threadIdx.x >> 6, l = threadIdx.x & 63;
    const float* row = h + (size_t)n * 512 + hh * 128;
    float x0 = row[l], x1 = row[l + 64];
    float s0 = x0 * a_s[hh * 128 + l] + x1 * a_s[hh * 128 + l + 64];
    float d0 = x0 * a_d[hh * 128 + l] + x1 * a_d[hh * 128 + l + 64];
    for (int o = 32; o; o >>= 1) { s0 += __shfl_down(s0, o); d0 += __shfl_down(d0, o); }
    if (l == 0) { ssrc[n * 4 + hh] = s0; sdst[n * 4 + hh] = d0; }
}

// ---------------------------------------------------------------------------
// CSR build: histogram of dst -> prefix scan -> fill (csr_src, csr_eid).
// ---------------------------------------------------------------------------
__global__ void hist_k(const int* __restrict__ ei, int E, int ET, int* __restrict__ deg) {
    int e = blockIdx.x * 256 + threadIdx.x;
    if (e >= ET) return;
    int d = (e < E) ? ei[E + e] : e - E;
    atomicAdd(&deg[d], 1);
}

// Single-block exclusive scan over deg[Nn] -> rowptr[Nn+1], cursor[Nn].
__global__ __launch_bounds__(1024) void scan_k(const int* __restrict__ deg,
                                               int* __restrict__ rowptr,
                                               int* __restrict__ cursor, int Nn) {
    __shared__ int part[1024];
    int t = threadIdx.x;
    int per = (Nn + 1023) / 1024;
    int b0 = t * per, b1 = min(b0 + per, Nn);
    int s = 0;
    for (int i = b0; i < b1; i++) s += deg[i];
    part[t] = s;
    __syncthreads();
    for (int o = 1; o < 1024; o <<= 1) {
        int x = (t >= o) ? part[t - o] : 0;
        __syncthreads();
        part[t] += x;
        __syncthreads();
    }
    int off = part[t] - s;   // exclusive prefix for this thread's range
    for (int i = b0; i < b1; i++) {
        rowptr[i] = off; cursor[i] = off; off += deg[i];
    }
    if (t == 1023) rowptr[Nn] = part[1023];
}

__global__ void fill_csr_k(const int* __restrict__ ei, int E, int ET,
                           int* __restrict__ cursor,
                           int* __restrict__ csr_src, int* __restrict__ csr_eid) {
    int e = blockIdx.x * 256 + threadIdx.x;
    if (e >= ET) return;
    int s, d;
    if (e < E) { s = ei[e]; d = ei[E + e]; } else { s = d = e - E; }
    int pos = atomicAdd(&cursor[d], 1);
    csr_src[pos] = s;
    csr_eid[pos] = e;
}

// ---------------------------------------------------------------------------
// Fused per-destination softmax + aggregate. One wave per dst (4 dst/block).
// concat=0: head-mean -> out[Nn,128].  concat=1: out[Nn,512] (+alpha to aout).
// ---------------------------------------------------------------------------
__global__ __launch_bounds__(256) void gat_agg(const int* __restrict__ rowptr,
                                               const int* __restrict__ csr_src,
                                               const int* __restrict__ csr_eid,
                                               const float4* __restrict__ ssrc,
                                               const float4* __restrict__ sdst,
                                               const float* __restrict__ hfeat,
                                               float* __restrict__ out,
                                               float4* __restrict__ aout,
                                               int Nn, int concat) {
    const int lane = threadIdx.x & 63;
    const int d = blockIdx.x * 4 + (threadIdx.x >> 6);
    if (d >= Nn) return;
    const int beg = rowptr[d], end = rowptr[d + 1];
    const float4 sd = sdst[d];
    const float NINF = -__builtin_huge_valf();

    // per-head running max over incoming edges
    float4 m = make_float4(NINF, NINF, NINF, NINF);
    for (int i = beg + lane; i < end; i += 64) {
        float4 ev = lrelu4(add4(ssrc[csr_src[i]], sd));
        m.x = fmaxf(m.x, ev.x); m.y = fmaxf(m.y, ev.y);
        m.z = fmaxf(m.z, ev.z); m.w = fmaxf(m.w, ev.w);
    }
    for (int o = 32; o; o >>= 1) {
        m.x = fmaxf(m.x, __shfl_xor(m.x, o));
        m.y = fmaxf(m.y, __shfl_xor(m.y, o));
        m.z = fmaxf(m.z, __shfl_xor(m.z, o));
        m.w = fmaxf(m.w, __shfl_xor(m.w, o));
    }

    // denominator
    float4 den = make_float4(0.f, 0.f, 0.f, 0.f);
    for (int i = beg + lane; i < end; i += 64) {
        float4 ev = lrelu4(add4(ssrc[csr_src[i]], sd));
        den.x += __expf(ev.x - m.x); den.y += __expf(ev.y - m.y);
        den.z += __expf(ev.z - m.z); den.w += __expf(ev.w - m.w);
    }
    for (int o = 32; o; o >>= 1) {
        den.x += __shfl_xor(den.x, o);
        den.y += __shfl_xor(den.y, o);
        den.z += __shfl_xor(den.z, o);
        den.w += __shfl_xor(den.w, o);
    }

    // aggregate: lane owns channels [lane*8, lane*8+8); head = lane>>4
    const int head = lane >> 4;
    float acc[8] = {};
    for (int i = beg; i < end; ++i) {
        int s = csr_src[i];
        float4 ev = lrelu4(add4(ssrc[s], sd));          // uniform across wave
        float4 a4;
        a4.x = __expf(ev.x - m.x) / den.x;
        a4.y = __expf(ev.y - m.y) / den.y;
        a4.z = __expf(ev.z - m.z) / den.z;
        a4.w = __expf(ev.w - m.w) / den.w;
        if (aout != nullptr && lane == 0) aout[csr_eid[i]] = a4;
        float a = (head == 0) ? a4.x : (head == 1) ? a4.y : (head == 2) ? a4.z : a4.w;
        const float4* row = (const float4*)(hfeat + (size_t)s * 512 + lane * 8);
        float4 v0 = row[0], v1 = row[1];
        acc[0] += a * v0.x; acc[1] += a * v0.y; acc[2] += a * v0.z; acc[3] += a * v0.w;
        acc[4] += a * v1.x; acc[5] += a * v1.y; acc[6] += a * v1.z; acc[7] += a * v1.w;
    }

    if (concat) {
        float4* orow = (float4*)(out + (size_t)d * 512 + lane * 8);
        orow[0] = make_float4(acc[0], acc[1], acc[2], acc[3]);
        orow[1] = make_float4(acc[4], acc[5], acc[6], acc[7]);
    } else {
        // head-mean: lanes {l, l^16, l^32, l^48} hold same within-head channels
#pragma unroll
        for (int k = 0; k < 8; k++) acc[k] += __shfl_xor(acc[k], 16);
#pragma unroll
        for (int k = 0; k < 8; k++) acc[k] += __shfl_xor(acc[k], 32);
        if (lane < 16) {
            float4* orow = (float4*)(out + (size_t)d * 128 + lane * 8);
            orow[0] = make_float4(0.25f * acc[0], 0.25f * acc[1], 0.25f * acc[2], 0.25f * acc[3]);
            orow[1] = make_float4(0.25f * acc[4], 0.25f * acc[5], 0.25f * acc[6], 0.25f * acc[7]);
        }
    }
}

// x = lrelu(LN(x + b1)) per node row of 128; one wave per node.
__global__ __launch_bounds__(256) void ln_lrelu(float* __restrict__ hbuf,
                                                const float* __restrict__ b1,
                                                const float* __restrict__ gg,
                                                const float* __restrict__ bb, int Nn) {
    int w = threadIdx.x >> 6, l = threadIdx.x & 63;
    int n = blockIdx.x * 4 + w;
    if (n >= Nn) return;
    float* row = hbuf + (size_t)n * 128;
    float x0 = row[l] + b1[l], x1 = row[l + 64] + b1[l + 64];
    float s = x0 + x1;
    for (int o = 32; o; o >>= 1) s += __shfl_down(s, o);
    s = __shfl(s, 0);
    float mu = s * (1.f / 128.f);
    float d0 = x0 - mu, d1 = x1 - mu;
    float v = d0 * d0 + d1 * d1;
    for (int o = 32; o; o >>= 1) v += __shfl_down(v, o);
    v = __shfl(v, 0);
    float r = rsqrtf(v * (1.f / 128.f) + 1e-5f);
    float y0 = gg[l] * d0 * r + bb[l];
    float y1 = gg[l + 64] * d1 * r + bb[l + 64];
    row[l]      = lrelu(y0);
    row[l + 64] = lrelu(y1);
}

// pooled[g,c] += sum over nodes of lrelu(out2[n,c]+b2[c]); batch is sorted.
__global__ __launch_bounds__(512) void pool_k(const float* __restrict__ out2,
                                              const float* __restrict__ b2,
                                              const int* __restrict__ batch,
                                              float* __restrict__ pooled, int Nn) {
    int c = threadIdx.x;
    int n0 = blockIdx.x * 64, n1 = min(n0 + 64, Nn);
    if (n0 >= Nn) return;
    float bc = b2[c];
    int g = batch[n0];
    float acc = 0.f;
    for (int n = n0; n < n1; ++n) {
        int bg = batch[n];
        if (bg != g) { atomicAdd(&pooled[g * 512 + c], acc); acc = 0.f; g = bg; }
        float v = out2[(size_t)n * 512 + c] + bc;
        acc += lrelu(v);
    }
    atomicAdd(&pooled[g * 512 + c], acc);
}

__global__ void count_k(const int* __restrict__ batch, float* __restrict__ cnt, int Nn) {
    int i = blockIdx.x * blockDim.x + threadIdx.x;
    if (i < Nn) atomicAdd(&cnt[batch[i]], 1.f);
}

// ---------------------------------------------------------------------------
// MLP head (G=64 rows).
// ---------------------------------------------------------------------------
__device__ __forceinline__ float block_sum(float v, volatile float* sbuf, int tid, int nw) {
    for (int o = 32; o; o >>= 1) v += __shfl_down(v, o);
    if ((tid & 63) == 0) sbuf[tid >> 6] = v;
    __syncthreads();
    if (tid == 0) { float r = 0.f; for (int i = 0; i < nw; i++) r += sbuf[i]; sbuf[0] = r; }
    __syncthreads();
    float r = sbuf[0];
    __syncthreads();
    return r;
}

__global__ __launch_bounds__(128) void lin0_k(const float* __restrict__ pooled,
                                              const float* __restrict__ cnt,
                                              const float* __restrict__ W,
                                              const float* __restrict__ b,
                                              float* __restrict__ z0) {
    int g = blockIdx.x, j = threadIdx.x;
    float inv = 1.f / fmaxf(cnt[g], 1.f);
    float acc = 0.f;
    for (int k = 0; k < 512; k++) acc += pooled[g * 512 + k] * W[k * 128 + j];
    z0[g * 128 + j] = acc * inv + b[j];
}

__global__ __launch_bounds__(256) void lin1_k(const float* __restrict__ z0,
                                              const float* __restrict__ W,
                                              const float* __restrict__ b,
                                              const float* __restrict__ gw,
                                              const float* __restrict__ gb,
                                              float* __restrict__ z1) {
    __shared__ float sbuf[8];
    int g = blockIdx.x, j = threadIdx.x;
    float acc = b[j];
    for (int k = 0; k < 128; k++) acc += z0[g * 128 + k] * W[k * 256 + j];
    float mu = block_sum(acc, sbuf, j, 4) * (1.f / 256.f);
    float d = acc - mu;
    float var = block_sum(d * d, sbuf, j, 4) * (1.f / 256.f);
    float y = gw[j] * d * rsqrtf(var + 1e-5f) + gb[j];
    z1[g * 256 + j] = fmaxf(y, 0.f);
}

__global__ __launch_bounds__(128) void lin2_k(const float* __restrict__ z1,
                                              const float* __restrict__ W,
                                              const float* __restrict__ b,
                                              const float* __restrict__ gw,
                                              const float* __restrict__ gb,
                                              float* __restrict__ z2) {
    __shared__ float sbuf[8];
    int g = blockIdx.x, j = threadIdx.x;
    float acc = b[j];
    for (int k = 0; k < 256; k++) acc += z1[g * 256 + k] * W[k * 128 + j];
    float mu = block_sum(acc, sbuf, j, 2) * (1.f / 128.f);
    float d = acc - mu;
    float var = block_sum(d * d, sbuf, j, 2) * (1.f / 128.f);
    float y = gw[j] * d * rsqrtf(var + 1e-5f) + gb[j];
    z2[g * 128 + j] = fmaxf(y, 0.f);
}

__global__ __launch_bounds__(64) void lin3_k(const float* __restrict__ z2,
                                             const float* __restrict__ W,
                                             const float* __restrict__ b,
                                             float* __restrict__ probs) {
    int g = blockIdx.x, l = threadIdx.x;
    float p0 = 0.f, p1 = 0.f;
    for (int k = l; k < 128; k += 64) {
        float z = z2[g * 128 + k];
        p0 += z * W[k * 2 + 0];
        p1 += z * W[k * 2 + 1];
    }
    for (int o = 32; o; o >>= 1) { p0 += __shfl_down(p0, o); p1 += __shfl_down(p1, o); }
    if (l == 0) {
        p0 += b[0]; p1 += b[1];
        float mx = fmaxf(p0, p1);
        float e0 = __expf(p0 - mx), e1 = __expf(p1 - mx);
        float s = e0 + e1;
        probs[g * 2 + 0] = e0 / s;
        probs[g * 2 + 1] = e1 / s;
    }
}

// ---------------------------------------------------------------------------
extern "C" void kernel_launch(void* const* d_in, const int* in_sizes, int n_in,
                              void* d_out, int out_size, void* d_ws, size_t ws_size,
                              hipStream_t stream) {
    const float* x    = (const float*)d_in[0];
    const int*   ei   = (const int*)d_in[1];
    const int*   batch= (const int*)d_in[2];
    const float* W1   = (const float*)d_in[3];
    const float* as1  = (const float*)d_in[4];
    const float* ad1  = (const float*)d_in[5];
    const float* b1   = (const float*)d_in[6];
    const float* g_ln = (const float*)d_in[7];
    const float* b_ln = (const float*)d_in[8];
    const float* W2   = (const float*)d_in[9];
    const float* as2  = (const float*)d_in[10];
    const float* ad2  = (const float*)d_in[11];
    const float* b2   = (const float*)d_in[12];
    const float* Wl0  = (const float*)d_in[13];
    const float* bl0  = (const float*)d_in[14];
    const float* Ws1  = (const float*)d_in[15];
    const float* bs1  = (const float*)d_in[16];
    const float* g1   = (const float*)d_in[17];
    const float* bb1  = (const float*)d_in[18];
    const float* Ws2  = (const float*)d_in[19];
    const float* bs2  = (const float*)d_in[20];
    const float* g2   = (const float*)d_in[21];
    const float* bb2  = (const float*)d_in[22];
    const float* Ws3  = (const float*)d_in[23];
    const float* bs3  = (const float*)d_in[24];
    (void)n_in; (void)out_size; (void)ws_size;

    const int Nn = in_sizes[0] / 128;   // 30000
    const int E  = in_sizes[1] / 2;     // 480000
    const int ET = E + Nn;              // 510000
    const int G  = 64;

    // ---- workspace layout ----
    char* ws = (char*)d_ws;
    size_t off = 0;
    auto alloc = [&](size_t bytes) { void* p = ws + off; off += (bytes + 255) & ~(size_t)255; return p; };
    float* h_a    = (float*)alloc((size_t)Nn * 512 * 4);   // h1, later h2
    float* hln    = (float*)alloc((size_t)Nn * 128 * 4);   // layer1 out -> LN in place
    float* out2   = (float*)alloc((size_t)Nn * 512 * 4);
    float* pooled = (float*)alloc((size_t)G * 512 * 4);
    float* cnt    = (float*)alloc((size_t)G * 4);
    float* z0     = (float*)alloc((size_t)G * 128 * 4);
    float* z1     = (float*)alloc((size_t)G * 256 * 4);
    float* z2     = (float*)alloc((size_t)G * 128 * 4);
    float* ssrc   = (float*)alloc((size_t)Nn * 4 * 4);
    float* sdst   = (float*)alloc((size_t)Nn * 4 * 4);
    int*   deg    = (int*)alloc((size_t)Nn * 4);
    int*   rowptr = (int*)alloc((size_t)(Nn + 1) * 4);
    int*   cursor = (int*)alloc((size_t)Nn * 4);
    int*   csr_src= (int*)alloc((size_t)ET * 4);
    int*   csr_eid= (int*)alloc((size_t)ET * 4);

    float* probs = (float*)d_out;
    float* aout  = (float*)d_out + 128;   // alpha [ET,4]

    // ---- init (ws poisoned 0xAA every call) ----
    hipMemsetAsync(deg, 0, (size_t)Nn * 4, stream);
    hipMemsetAsync(pooled, 0, (size_t)G * 512 * 4 + (size_t)G * 4, stream); // pooled+cnt contiguous

    const int eblks = (ET + 255) / 256;
    dim3 ggrid((Nn + 63) / 64, 8);
    const int ablks = (Nn + 3) / 4;

    // ---- CSR build (dst segments shared by both layers) ----
    hist_k<<<eblks, 256, 0, stream>>>(ei, E, ET, deg);
    scan_k<<<1, 1024, 0, stream>>>(deg, rowptr, cursor, Nn);
    fill_csr_k<<<eblks, 256, 0, stream>>>(ei, E, ET, cursor, csr_src, csr_eid);

    // ---- layer 1 ----
    gemm128<<<ggrid, 256, 0, stream>>>(x, W1, h_a, Nn, 512);
    heads_dot<<<Nn, 256, 0, stream>>>(h_a, as1, ad1, ssrc, sdst);
    gat_agg<<<ablks, 256, 0, stream>>>(rowptr, csr_src, csr_eid,
                                       (const float4*)ssrc, (const float4*)sdst,
                                       h_a, hln, nullptr, Nn, 0);
    ln_lrelu<<<ablks, 256, 0, stream>>>(hln, b1, g_ln, b_ln, Nn);

    // ---- layer 2 ----
    gemm128<<<ggrid, 256, 0, stream>>>(hln, W2, h_a, Nn, 512);
    heads_dot<<<Nn, 256, 0, stream>>>(h_a, as2, ad2, ssrc, sdst);
    gat_agg<<<ablks, 256, 0, stream>>>(rowptr, csr_src, csr_eid,
                                       (const float4*)ssrc, (const float4*)sdst,
                                       h_a, out2, (float4*)aout, Nn, 1);

    // ---- pool + MLP head ----
    pool_k<<<(Nn + 63) / 64, 512, 0, stream>>>(out2, b2, batch, pooled, Nn);
    count_k<<<(Nn + 255) / 256, 256, 0, stream>>>(batch, cnt, Nn);
    lin0_k<<<G, 128, 0, stream>>>(pooled, cnt, Wl0, bl0, z0);
    lin1_k<<<G, 256, 0, stream>>>(z0, Ws1, bs1, g1, bb1, z1);
    lin2_k<<<G, 128, 0, stream>>>(z1, Ws2, bs2, g2, bb2, z2);
    lin3_k<<<G, 64, 0, stream>>>(z2, Ws3, bs3, probs);
}

// Round 8
// 759.032 us; speedup vs baseline: 2.9319x; 1.2868x over previous
//
#include <hip/hip_runtime.h>
#include <cstdint>
#include <cstddef>

// ---------------------------------------------------------------------------
// GAT forward: N=30000, E=480000 (+N self loops), ATOM=HID=128, H=4, OUT=256
// All fp32. Outputs: probs [64,2] then alpha2 [E+N, 4], flat in d_out.
// R2: CSR-by-destination + per-wave softmax/aggregate (no edge atomics).
// R7: count via binary search on sorted batch (was 181us of atomic chains);
//     gat_agg: chunked lane-parallel alpha precompute into per-wave LDS
//     (kills 64x-redundant exp in the gather loop), parallel alpha store.
// ---------------------------------------------------------------------------

__device__ __forceinline__ float lrelu(float v) { return v >= 0.f ? v : 0.2f * v; }

__device__ __forceinline__ float4 lrelu4(float4 v) {
    return make_float4(lrelu(v.x), lrelu(v.y), lrelu(v.z), lrelu(v.w));
}
__device__ __forceinline__ float4 add4(float4 a, float4 b) {
    return make_float4(a.x + b.x, a.y + b.y, a.z + b.z, a.w + b.w);
}

// ---------------------------------------------------------------------------
// C[M,512] = A[M,128] @ B[128,512].  64x64 tile, 256 threads, 4x4 per thread.
// ---------------------------------------------------------------------------
__global__ __launch_bounds__(256) void gemm128(const float* __restrict__ A,
                                               const float* __restrict__ B,
                                               float* __restrict__ C, int M, int N) {
    __shared__ float As[64][132];
    __shared__ float Bs[128][64];
    const int tid  = threadIdx.x;
    const int row0 = blockIdx.x * 64, col0 = blockIdx.y * 64;

#pragma unroll
    for (int i = 0; i < 8; i++) {                // A tile: 64 rows x 128 cols
        int idx = tid + i * 256;
        int r = idx >> 5, c4 = idx & 31;
        int gr = row0 + r;
        float4 v = make_float4(0.f, 0.f, 0.f, 0.f);
        if (gr < M) v = *(const float4*)&A[(size_t)gr * 128 + c4 * 4];
        *(float4*)&As[r][c4 * 4] = v;
    }
#pragma unroll
    for (int i = 0; i < 8; i++) {                // B tile: 128 rows x 64 cols
        int idx = tid + i * 256;
        int r = idx >> 4, c4 = idx & 15;
        *(float4*)&Bs[r][c4 * 4] = *(const float4*)&B[(size_t)r * N + col0 + c4 * 4];
    }
    __syncthreads();

    const int tx = tid & 15, ty = tid >> 4;
    float acc[4][4] = {};
#pragma unroll 2
    for (int k = 0; k < 128; k += 4) {
        float4 a[4], b[4];
#pragma unroll
        for (int i = 0; i < 4; i++) a[i] = *(const float4*)&As[ty * 4 + i][k];
#pragma unroll
        for (int j = 0; j < 4; j++) b[j] = *(const float4*)&Bs[k + j][tx * 4];
#pragma unroll
        for (int i = 0; i < 4; i++) {
            acc[i][0] += a[i].x * b[0].x + a[i].y * b[1].x + a[i].z * b[2].x + a[i].w * b[3].x;
            acc[i][1] += a[i].x * b[0].y + a[i].y * b[1].y + a[i].z * b[2].y + a[i].w * b[3].y;
            acc[i][2] += a[i].x * b[0].z + a[i].y * b[1].z + a[i].z * b[2].z + a[i].w * b[3].z;
            acc[i][3] += a[i].x * b[0].w + a[i].y * b[1].w + a[i].z * b[2].w + a[i].w * b[3].w;
        }
    }
#pragma unroll
    for (int i = 0; i < 4; i++) {
        int gr = row0 + ty * 4 + i;
        if (gr < M)
            *(float4*)&C[(size_t)gr * N + col0 + tx * 4] =
                make_float4(acc[i][0], acc[i][1], acc[i][2], acc[i][3]);
    }
}

// ---------------------------------------------------------------------------
// Per-node, per-head scores: ssrc[n,h] = sum_c h[n,h,c]*a_s[h,c]; same for sdst.
// ---------------------------------------------------------------------------
__global__ __launch_bounds__(256) void heads_dot(const float* __restrict__ h,
                                                 const float* __restrict__ a_s,
                                                 const float* __restrict__ a_d,
                                                 float* __restrict__ ssrc,
                                                 float* __restrict__ sdst) {
    int n = blockIdx.x;
    int hh = threadIdx.x >> 6, l = threadIdx.x & 63;
    const float* row = h + (size_t)n * 512 + hh * 128;
    float x0 = row[l], x1 = row[l + 64];
    float s0 = x0 * a_s[hh * 128 + l] + x1 * a_s[hh * 128 + l + 64];
    float d0 = x0 * a_d[hh * 128 + l] + x1 * a_d[hh * 128 + l + 64];
    for (int o = 32; o; o >>= 1) { s0 += __shfl_down(s0, o); d0 += __shfl_down(d0, o); }
    if (l == 0) { ssrc[n * 4 + hh] = s0; sdst[n * 4 + hh] = d0; }
}

// ---------------------------------------------------------------------------
// CSR build: histogram of dst -> prefix scan -> fill (csr_src, csr_eid).
// ---------------------------------------------------------------------------
__global__ void hist_k(const int* __restrict__ ei, int E, int ET, int* __restrict__ deg) {
    int e = blockIdx.x * 256 + threadIdx.x;
    if (e >= ET) return;
    int d = (e < E) ? ei[E + e] : e - E;
    atomicAdd(&deg[d], 1);
}

// Single-block exclusive scan over deg[Nn] -> rowptr[Nn+1], cursor[Nn].
__global__ __launch_bounds__(1024) void scan_k(const int* __restrict__ deg,
                                               int* __restrict__ rowptr,
                                               int* __restrict__ cursor, int Nn) {
    __shared__ int part[1024];
    int t = threadIdx.x;
    int per = (Nn + 1023) / 1024;
    int b0 = t * per, b1 = min(b0 + per, Nn);
    int s = 0;
    for (int i = b0; i < b1; i++) s += deg[i];
    part[t] = s;
    __syncthreads();
    for (int o = 1; o < 1024; o <<= 1) {
        int x = (t >= o) ? part[t - o] : 0;
        __syncthreads();
        part[t] += x;
        __syncthreads();
    }
    int off = part[t] - s;   // exclusive prefix for this thread's range
    for (int i = b0; i < b1; i++) {
        rowptr[i] = off; cursor[i] = off; off += deg[i];
    }
    if (t == 1023) rowptr[Nn] = part[1023];
}

__global__ void fill_csr_k(const int* __restrict__ ei, int E, int ET,
                           int* __restrict__ cursor,
                           int* __restrict__ csr_src, int* __restrict__ csr_eid) {
    int e = blockIdx.x * 256 + threadIdx.x;
    if (e >= ET) return;
    int s, d;
    if (e < E) { s = ei[e]; d = ei[E + e]; } else { s = d = e - E; }
    int pos = atomicAdd(&cursor[d], 1);
    csr_src[pos] = s;
    csr_eid[pos] = e;
}

// ---------------------------------------------------------------------------
// Fused per-destination softmax + aggregate. One wave per dst (4 dst/block).
// concat=0: head-mean -> out[Nn,128].  concat=1: out[Nn,512] (+alpha to aout).
// Alpha precomputed lane-parallel in 64-edge chunks into per-wave LDS; the
// serial gather loop then only does LDS read + row FMA (no wave-wide exp).
// ---------------------------------------------------------------------------
__global__ __launch_bounds__(256) void gat_agg(const int* __restrict__ rowptr,
                                               const int* __restrict__ csr_src,
                                               const int* __restrict__ csr_eid,
                                               const float4* __restrict__ ssrc,
                                               const float4* __restrict__ sdst,
                                               const float* __restrict__ hfeat,
                                               float* __restrict__ out,
                                               float4* __restrict__ aout,
                                               int Nn, int concat) {
    __shared__ float alds[4][64][4];   // per-wave alpha slab (wave-private)
    const int lane = threadIdx.x & 63;
    const int w = threadIdx.x >> 6;
    const int d = blockIdx.x * 4 + w;
    if (d >= Nn) return;
    const int beg = rowptr[d], end = rowptr[d + 1];
    const float4 sd = sdst[d];
    const float NINF = -__builtin_huge_valf();

    // per-head running max over incoming edges
    float4 m = make_float4(NINF, NINF, NINF, NINF);
    for (int i = beg + lane; i < end; i += 64) {
        float4 ev = lrelu4(add4(ssrc[csr_src[i]], sd));
        m.x = fmaxf(m.x, ev.x); m.y = fmaxf(m.y, ev.y);
        m.z = fmaxf(m.z, ev.z); m.w = fmaxf(m.w, ev.w);
    }
    for (int o = 32; o; o >>= 1) {
        m.x = fmaxf(m.x, __shfl_xor(m.x, o));
        m.y = fmaxf(m.y, __shfl_xor(m.y, o));
        m.z = fmaxf(m.z, __shfl_xor(m.z, o));
        m.w = fmaxf(m.w, __shfl_xor(m.w, o));
    }

    // denominator
    float4 den = make_float4(0.f, 0.f, 0.f, 0.f);
    for (int i = beg + lane; i < end; i += 64) {
        float4 ev = lrelu4(add4(ssrc[csr_src[i]], sd));
        den.x += __expf(ev.x - m.x); den.y += __expf(ev.y - m.y);
        den.z += __expf(ev.z - m.z); den.w += __expf(ev.w - m.w);
    }
    for (int o = 32; o; o >>= 1) {
        den.x += __shfl_xor(den.x, o);
        den.y += __shfl_xor(den.y, o);
        den.z += __shfl_xor(den.z, o);
        den.w += __shfl_xor(den.w, o);
    }
    float4 inv;
    inv.x = 1.f / den.x; inv.y = 1.f / den.y;
    inv.z = 1.f / den.z; inv.w = 1.f / den.w;

    // aggregate: lane owns channels [lane*8, lane*8+8); head = lane>>4
    const int head = lane >> 4;
    float acc[8] = {};
    for (int chunk = beg; chunk < end; chunk += 64) {
        const int n = min(64, end - chunk);
        if (lane < n) {
            int i = chunk + lane;
            float4 ev = lrelu4(add4(ssrc[csr_src[i]], sd));
            float4 a4;
            a4.x = __expf(ev.x - m.x) * inv.x;
            a4.y = __expf(ev.y - m.y) * inv.y;
            a4.z = __expf(ev.z - m.z) * inv.z;
            a4.w = __expf(ev.w - m.w) * inv.w;
            alds[w][lane][0] = a4.x; alds[w][lane][1] = a4.y;
            alds[w][lane][2] = a4.z; alds[w][lane][3] = a4.w;
            if (aout != nullptr) aout[csr_eid[i]] = a4;
        }
        // wave-private LDS: in-order per-wave DS ops, no barrier needed
        for (int j = 0; j < n; ++j) {
            int s = csr_src[chunk + j];
            float a = alds[w][j][head];
            const float4* row = (const float4*)(hfeat + (size_t)s * 512 + lane * 8);
            float4 v0 = row[0], v1 = row[1];
            acc[0] += a * v0.x; acc[1] += a * v0.y; acc[2] += a * v0.z; acc[3] += a * v0.w;
            acc[4] += a * v1.x; acc[5] += a * v1.y; acc[6] += a * v1.z; acc[7] += a * v1.w;
        }
    }

    if (concat) {
        float4* orow = (float4*)(out + (size_t)d * 512 + lane * 8);
        orow[0] = make_float4(acc[0], acc[1], acc[2], acc[3]);
        orow[1] = make_float4(acc[4], acc[5], acc[6], acc[7]);
    } else {
        // head-mean: lanes {l, l^16, l^32, l^48} hold same within-head channels
#pragma unroll
        for (int k = 0; k < 8; k++) acc[k] += __shfl_xor(acc[k], 16);
#pragma unroll
        for (int k = 0; k < 8; k++) acc[k] += __shfl_xor(acc[k], 32);
        if (lane < 16) {
            float4* orow = (float4*)(out + (size_t)d * 128 + lane * 8);
            orow[0] = make_float4(0.25f * acc[0], 0.25f * acc[1], 0.25f * acc[2], 0.25f * acc[3]);
            orow[1] = make_float4(0.25f * acc[4], 0.25f * acc[5], 0.25f * acc[6], 0.25f * acc[7]);
        }
    }
}

// x = lrelu(LN(x + b1)) per node row of 128; one wave per node.
__global__ __launch_bounds__(256) void ln_lrelu(float* __restrict__ hbuf,
                                                const float* __restrict__ b1,
                                                const float* __restrict__ gg,
                                                const float* __restrict__ bb, int Nn) {
    int w = threadIdx.x >> 6, l = threadIdx.x & 63;
    int n = blockIdx.x * 4 + w;
    if (n >= Nn) return;
    float* row = hbuf + (size_t)n * 128;
    float x0 = row[l] + b1[l], x1 = row[l + 64] + b1[l + 64];
    float s = x0 + x1;
    for (int o = 32; o; o >>= 1) s += __shfl_down(s, o);
    s = __shfl(s, 0);
    float mu = s * (1.f / 128.f);
    float d0 = x0 - mu, d1 = x1 - mu;
    float v = d0 * d0 + d1 * d1;
    for (int o = 32; o; o >>= 1) v += __shfl_down(v, o);
    v = __shfl(v, 0);
    float r = rsqrtf(v * (1.f / 128.f) + 1e-5f);
    float y0 = gg[l] * d0 * r + bb[l];
    float y1 = gg[l + 64] * d1 * r + bb[l + 64];
    row[l]      = lrelu(y0);
    row[l + 64] = lrelu(y1);
}

// pooled[g,c] += sum over nodes of lrelu(out2[n,c]+b2[c]); batch is sorted.
__global__ __launch_bounds__(512) void pool_k(const float* __restrict__ out2,
                                              const float* __restrict__ b2,
                                              const int* __restrict__ batch,
                                              float* __restrict__ pooled, int Nn) {
    int c = threadIdx.x;
    int n0 = blockIdx.x * 64, n1 = min(n0 + 64, Nn);
    if (n0 >= Nn) return;
    float bc = b2[c];
    int g = batch[n0];
    float acc = 0.f;
    for (int n = n0; n < n1; ++n) {
        int bg = batch[n];
        if (bg != g) { atomicAdd(&pooled[g * 512 + c], acc); acc = 0.f; g = bg; }
        float v = out2[(size_t)n * 512 + c] + bc;
        acc += lrelu(v);
    }
    atomicAdd(&pooled[g * 512 + c], acc);
}

// batch is sorted: cnt[g] = lower_bound(g+1) - lower_bound(g). One block, no atomics.
__global__ __launch_bounds__(64) void count_sorted_k(const int* __restrict__ batch,
                                                     float* __restrict__ cnt, int Nn, int G) {
    int g = threadIdx.x;
    if (g >= G) return;
    int lo = 0, hi = Nn;
    while (lo < hi) { int mid = (lo + hi) >> 1; if (batch[mid] < g) lo = mid + 1; else hi = mid; }
    int a = lo;
    lo = 0; hi = Nn;
    while (lo < hi) { int mid = (lo + hi) >> 1; if (batch[mid] < g + 1) lo = mid + 1; else hi = mid; }
    cnt[g] = (float)(lo - a);
}

// ---------------------------------------------------------------------------
// MLP head (G=64 rows).
// ---------------------------------------------------------------------------
__device__ __forceinline__ float block_sum(float v, volatile float* sbuf, int tid, int nw) {
    for (int o = 32; o; o >>= 1) v += __shfl_down(v, o);
    if ((tid & 63) == 0) sbuf[tid >> 6] = v;
    __syncthreads();
    if (tid == 0) { float r = 0.f; for (int i = 0; i < nw; i++) r += sbuf[i]; sbuf[0] = r; }
    __syncthreads();
    float r = sbuf[0];
    __syncthreads();
    return r;
}

__global__ __launch_bounds__(128) void lin0_k(const float* __restrict__ pooled,
                                              const float* __restrict__ cnt,
                                              const float* __restrict__ W,
                                              const float* __restrict__ b,
                                              float* __restrict__ z0) {
    int g = blockIdx.x, j = threadIdx.x;
    float inv = 1.f / fmaxf(cnt[g], 1.f);
    float acc = 0.f;
    for (int k = 0; k < 512; k++) acc += pooled[g * 512 + k] * W[k * 128 + j];
    z0[g * 128 + j] = acc * inv + b[j];
}

__global__ __launch_bounds__(256) void lin1_k(const float* __restrict__ z0,
                                              const float* __restrict__ W,
                                              const float* __restrict__ b,
                                              const float* __restrict__ gw,
                                              const float* __restrict__ gb,
                                              float* __restrict__ z1) {
    __shared__ float sbuf[8];
    int g = blockIdx.x, j = threadIdx.x;
    float acc = b[j];
    for (int k = 0; k < 128; k++) acc += z0[g * 128 + k] * W[k * 256 + j];
    float mu = block_sum(acc, sbuf, j, 4) * (1.f / 256.f);
    float d = acc - mu;
    float var = block_sum(d * d, sbuf, j, 4) * (1.f / 256.f);
    float y = gw[j] * d * rsqrtf(var + 1e-5f) + gb[j];
    z1[g * 256 + j] = fmaxf(y, 0.f);
}

__global__ __launch_bounds__(128) void lin2_k(const float* __restrict__ z1,
                                              const float* __restrict__ W,
                                              const float* __restrict__ b,
                                              const float* __restrict__ gw,
                                              const float* __restrict__ gb,
                                              float* __restrict__ z2) {
    __shared__ float sbuf[8];
    int g = blockIdx.x, j = threadIdx.x;
    float acc = b[j];
    for (int k = 0; k < 256; k++) acc += z1[g * 256 + k] * W[k * 128 + j];
    float mu = block_sum(acc, sbuf, j, 2) * (1.f / 128.f);
    float d = acc - mu;
    float var = block_sum(d * d, sbuf, j, 2) * (1.f / 128.f);
    float y = gw[j] * d * rsqrtf(var + 1e-5f) + gb[j];
    z2[g * 128 + j] = fmaxf(y, 0.f);
}

__global__ __launch_bounds__(64) void lin3_k(const float* __restrict__ z2,
                                             const float* __restrict__ W,
                                             const float* __restrict__ b,
                                             float* __restrict__ probs) {
    int g = blockIdx.x, l = threadIdx.x;
    float p0 = 0.f, p1 = 0.f;
    for (int k = l; k < 128; k += 64) {
        float z = z2[g * 128 + k];
        p0 += z * W[k * 2 + 0];
        p1 += z * W[k * 2 + 1];
    }
    for (int o = 32; o; o >>= 1) { p0 += __shfl_down(p0, o); p1 += __shfl_down(p1, o); }
    if (l == 0) {
        p0 += b[0]; p1 += b[1];
        float mx = fmaxf(p0, p1);
        float e0 = __expf(p0 - mx), e1 = __expf(p1 - mx);
        float s = e0 + e1;
        probs[g * 2 + 0] = e0 / s;
        probs[g * 2 + 1] = e1 / s;
    }
}

// ---------------------------------------------------------------------------
extern "C" void kernel_launch(void* const* d_in, const int* in_sizes, int n_in,
                              void* d_out, int out_size, void* d_ws, size_t ws_size,
                              hipStream_t stream) {
    const float* x    = (const float*)d_in[0];
    const int*   ei   = (const int*)d_in[1];
    const int*   batch= (const int*)d_in[2];
    const float* W1   = (const float*)d_in[3];
    const float* as1  = (const float*)d_in[4];
    const float* ad1  = (const float*)d_in[5];
    const float* b1   = (const float*)d_in[6];
    const float* g_ln = (const float*)d_in[7];
    const float* b_ln = (const float*)d_in[8];
    const float* W2   = (const float*)d_in[9];
    const float* as2  = (const float*)d_in[10];
    const float* ad2  = (const float*)d_in[11];
    const float* b2   = (const float*)d_in[12];
    const float* Wl0  = (const float*)d_in[13];
    const float* bl0  = (const float*)d_in[14];
    const float* Ws1  = (const float*)d_in[15];
    const float* bs1  = (const float*)d_in[16];
    const float* g1   = (const float*)d_in[17];
    const float* bb1  = (const float*)d_in[18];
    const float* Ws2  = (const float*)d_in[19];
    const float* bs2  = (const float*)d_in[20];
    const float* g2   = (const float*)d_in[21];
    const float* bb2  = (const float*)d_in[22];
    const float* Ws3  = (const float*)d_in[23];
    const float* bs3  = (const float*)d_in[24];
    (void)n_in; (void)out_size; (void)ws_size;

    const int Nn = in_sizes[0] / 128;   // 30000
    const int E  = in_sizes[1] / 2;     // 480000
    const int ET = E + Nn;              // 510000
    const int G  = 64;

    // ---- workspace layout ----
    char* ws = (char*)d_ws;
    size_t off = 0;
    auto alloc = [&](size_t bytes) { void* p = ws + off; off += (bytes + 255) & ~(size_t)255; return p; };
    float* h_a    = (float*)alloc((size_t)Nn * 512 * 4);   // h1, later h2
    float* hln    = (float*)alloc((size_t)Nn * 128 * 4);   // layer1 out -> LN in place
    float* out2   = (float*)alloc((size_t)Nn * 512 * 4);
    float* pooled = (float*)alloc((size_t)G * 512 * 4);
    float* cnt    = (float*)alloc((size_t)G * 4);
    float* z0     = (float*)alloc((size_t)G * 128 * 4);
    float* z1     = (float*)alloc((size_t)G * 256 * 4);
    float* z2     = (float*)alloc((size_t)G * 128 * 4);
    float* ssrc   = (float*)alloc((size_t)Nn * 4 * 4);
    float* sdst   = (float*)alloc((size_t)Nn * 4 * 4);
    int*   deg    = (int*)alloc((size_t)Nn * 4);
    int*   rowptr = (int*)alloc((size_t)(Nn + 1) * 4);
    int*   cursor = (int*)alloc((size_t)Nn * 4);
    int*   csr_src= (int*)alloc((size_t)ET * 4);
    int*   csr_eid= (int*)alloc((size_t)ET * 4);

    float* probs = (float*)d_out;
    float* aout  = (float*)d_out + 128;   // alpha [ET,4]

    // ---- init (ws poisoned 0xAA every call) ----
    hipMemsetAsync(deg, 0, (size_t)Nn * 4, stream);
    hipMemsetAsync(pooled, 0, (size_t)G * 512 * 4, stream);

    const int eblks = (ET + 255) / 256;
    dim3 ggrid((Nn + 63) / 64, 8);
    const int ablks = (Nn + 3) / 4;

    // ---- CSR build (dst segments shared by both layers) ----
    hist_k<<<eblks, 256, 0, stream>>>(ei, E, ET, deg);
    scan_k<<<1, 1024, 0, stream>>>(deg, rowptr, cursor, Nn);
    fill_csr_k<<<eblks, 256, 0, stream>>>(ei, E, ET, cursor, csr_src, csr_eid);

    // ---- layer 1 ----
    gemm128<<<ggrid, 256, 0, stream>>>(x, W1, h_a, Nn, 512);
    heads_dot<<<Nn, 256, 0, stream>>>(h_a, as1, ad1, ssrc, sdst);
    gat_agg<<<ablks, 256, 0, stream>>>(rowptr, csr_src, csr_eid,
                                       (const float4*)ssrc, (const float4*)sdst,
                                       h_a, hln, nullptr, Nn, 0);
    ln_lrelu<<<ablks, 256, 0, stream>>>(hln, b1, g_ln, b_ln, Nn);

    // ---- layer 2 ----
    gemm128<<<ggrid, 256, 0, stream>>>(hln, W2, h_a, Nn, 512);
    heads_dot<<<Nn, 256, 0, stream>>>(h_a, as2, ad2, ssrc, sdst);
    gat_agg<<<ablks, 256, 0, stream>>>(rowptr, csr_src, csr_eid,
                                       (const float4*)ssrc, (const float4*)sdst,
                                       h_a, out2, (float4*)aout, Nn, 1);

    // ---- pool + MLP head ----
    pool_k<<<(Nn + 63) / 64, 512, 0, stream>>>(out2, b2, batch, pooled, Nn);
    count_sorted_k<<<1, 64, 0, stream>>>(batch, cnt, Nn, G);
    lin0_k<<<G, 128, 0, stream>>>(pooled, cnt, Wl0, bl0, z0);
    lin1_k<<<G, 256, 0, stream>>>(z0, Ws1, bs1, g1, bb1, z1);
    lin2_k<<<G, 128, 0, stream>>>(z1, Ws2, bs2, g2, bb2, z2);
    lin3_k<<<G, 64, 0, stream>>>(z2, Ws3, bs3, probs);
}

// Round 10
// 646.990 us; speedup vs baseline: 3.4396x; 1.1732x over previous
//
#include <hip/hip_runtime.h>
#include <cstdint>
#include <cstddef>

// ---------------------------------------------------------------------------
// GAT forward: N=30000, E=480000 (+N self loops), ATOM=HID=128, H=4, OUT=256
// Outputs: probs [64,2] then alpha2 [E+N, 4], flat in d_out.
// R2: CSR-by-destination + per-wave softmax/aggregate (no edge atomics).
// R7: sorted-batch count (no atomics); lane-parallel alpha into per-wave LDS.
// R8: gat_agg gathers from a bf16 copy of h (halves L2-miss gather traffic;
//     scores still fp32); gemm computes 2 col-tiles per A-tile load.
// R9: identical resubmit (R9 bench was an acquisition timeout).
// ---------------------------------------------------------------------------

__device__ __forceinline__ float lrelu(float v) { return v >= 0.f ? v : 0.2f * v; }

__device__ __forceinline__ float4 lrelu4(float4 v) {
    return make_float4(lrelu(v.x), lrelu(v.y), lrelu(v.z), lrelu(v.w));
}
__device__ __forceinline__ float4 add4(float4 a, float4 b) {
    return make_float4(a.x + b.x, a.y + b.y, a.z + b.z, a.w + b.w);
}

// round-to-nearest-even float -> bf16 bits
__device__ __forceinline__ unsigned short f2bf(float x) {
    unsigned int u = __float_as_uint(x);
    u += 0x7FFFu + ((u >> 16) & 1u);
    return (unsigned short)(u >> 16);
}

// ---------------------------------------------------------------------------
// C[M,512] = A[M,128] @ B[128,512], plus bf16 copy Cb.
// 64-row tile; each block computes TWO 64-col tiles from one A-tile load.
// ---------------------------------------------------------------------------
__global__ __launch_bounds__(256) void gemm128(const float* __restrict__ A,
                                               const float* __restrict__ B,
                                               float* __restrict__ C,
                                               unsigned short* __restrict__ Cb,
                                               int M, int N) {
    __shared__ float As[64][132];
    __shared__ float Bs[128][64];
    const int tid  = threadIdx.x;
    const int row0 = blockIdx.x * 64;
    const int colbase = blockIdx.y * 128;

#pragma unroll
    for (int i = 0; i < 8; i++) {                // A tile: 64 rows x 128 cols
        int idx = tid + i * 256;
        int r = idx >> 5, c4 = idx & 31;
        int gr = row0 + r;
        float4 v = make_float4(0.f, 0.f, 0.f, 0.f);
        if (gr < M) v = *(const float4*)&A[(size_t)gr * 128 + c4 * 4];
        *(float4*)&As[r][c4 * 4] = v;
    }

    const int tx = tid & 15, ty = tid >> 4;

    for (int half = 0; half < 2; ++half) {
        const int col0 = colbase + half * 64;
        if (half) __syncthreads();               // compute(half0) done before Bs overwrite
#pragma unroll
        for (int i = 0; i < 8; i++) {            // B tile: 128 rows x 64 cols
            int idx = tid + i * 256;
            int r = idx >> 4, c4 = idx & 15;
            *(float4*)&Bs[r][c4 * 4] = *(const float4*)&B[(size_t)r * N + col0 + c4 * 4];
        }
        __syncthreads();

        float acc[4][4] = {};
#pragma unroll 2
        for (int k = 0; k < 128; k += 4) {
            float4 a[4], b[4];
#pragma unroll
            for (int i = 0; i < 4; i++) a[i] = *(const float4*)&As[ty * 4 + i][k];
#pragma unroll
            for (int j = 0; j < 4; j++) b[j] = *(const float4*)&Bs[k + j][tx * 4];
#pragma unroll
            for (int i = 0; i < 4; i++) {
                acc[i][0] += a[i].x * b[0].x + a[i].y * b[1].x + a[i].z * b[2].x + a[i].w * b[3].x;
                acc[i][1] += a[i].x * b[0].y + a[i].y * b[1].y + a[i].z * b[2].y + a[i].w * b[3].y;
                acc[i][2] += a[i].x * b[0].z + a[i].y * b[1].z + a[i].z * b[2].z + a[i].w * b[3].z;
                acc[i][3] += a[i].x * b[0].w + a[i].y * b[1].w + a[i].z * b[2].w + a[i].w * b[3].w;
            }
        }
#pragma unroll
        for (int i = 0; i < 4; i++) {
            int gr = row0 + ty * 4 + i;
            if (gr < M) {
                *(float4*)&C[(size_t)gr * N + col0 + tx * 4] =
                    make_float4(acc[i][0], acc[i][1], acc[i][2], acc[i][3]);
                ushort4 bv;
                bv.x = f2bf(acc[i][0]); bv.y = f2bf(acc[i][1]);
                bv.z = f2bf(acc[i][2]); bv.w = f2bf(acc[i][3]);
                *(ushort4*)&Cb[(size_t)gr * N + col0 + tx * 4] = bv;
            }
        }
    }
}

// ---------------------------------------------------------------------------
// Per-node, per-head scores: ssrc[n,h] = sum_c h[n,h,c]*a_s[h,c]; same for sdst.
// ---------------------------------------------------------------------------
__global__ __launch_bounds__(256) void heads_dot(const float* __restrict__ h,
                                                 const float* __restrict__ a_s,
                                                 const float* __restrict__ a_d,
                                                 float* __restrict__ ssrc,
                                                 float* __restrict__ sdst) {
    int n = blockIdx.x;
    int hh = threadIdx.x >> 6, l = threadIdx.x & 63;
    const float* row = h + (size_t)n * 512 + hh * 128;
    float x0 = row[l], x1 = row[l + 64];
    float s0 = x0 * a_s[hh * 128 + l] + x1 * a_s[hh * 128 + l + 64];
    float d0 = x0 * a_d[hh * 128 + l] + x1 * a_d[hh * 128 + l + 64];
    for (int o = 32; o; o >>= 1) { s0 += __shfl_down(s0, o); d0 += __shfl_down(d0, o); }
    if (l == 0) { ssrc[n * 4 + hh] = s0; sdst[n * 4 + hh] = d0; }
}

// ---------------------------------------------------------------------------
// CSR build: histogram of dst -> prefix scan -> fill (csr_src, csr_eid).
// ---------------------------------------------------------------------------
__global__ void hist_k(const int* __restrict__ ei, int E, int ET, int* __restrict__ deg) {
    int e = blockIdx.x * 256 + threadIdx.x;
    if (e >= ET) return;
    int d = (e < E) ? ei[E + e] : e - E;
    atomicAdd(&deg[d], 1);
}

// Single-block exclusive scan over deg[Nn] -> rowptr[Nn+1], cursor[Nn].
__global__ __launch_bounds__(1024) void scan_k(const int* __restrict__ deg,
                                               int* __restrict__ rowptr,
                                               int* __restrict__ cursor, int Nn) {
    __shared__ int part[1024];
    int t = threadIdx.x;
    int per = (Nn + 1023) / 1024;
    int b0 = t * per, b1 = min(b0 + per, Nn);
    int s = 0;
    for (int i = b0; i < b1; i++) s += deg[i];
    part[t] = s;
    __syncthreads();
    for (int o = 1; o < 1024; o <<= 1) {
        int x = (t >= o) ? part[t - o] : 0;
        __syncthreads();
        part[t] += x;
        __syncthreads();
    }
    int off = part[t] - s;   // exclusive prefix for this thread's range
    for (int i = b0; i < b1; i++) {
        rowptr[i] = off; cursor[i] = off; off += deg[i];
    }
    if (t == 1023) rowptr[Nn] = part[1023];
}

__global__ void fill_csr_k(const int* __restrict__ ei, int E, int ET,
                           int* __restrict__ cursor,
                           int* __restrict__ csr_src, int* __restrict__ csr_eid) {
    int e = blockIdx.x * 256 + threadIdx.x;
    if (e >= ET) return;
    int s, d;
    if (e < E) { s = ei[e]; d = ei[E + e]; } else { s = d = e - E; }
    int pos = atomicAdd(&cursor[d], 1);
    csr_src[pos] = s;
    csr_eid[pos] = e;
}

// ---------------------------------------------------------------------------
// Fused per-destination softmax + aggregate. One wave per dst (4 dst/block).
// Gathers from bf16 hb (16 B/lane). concat=0: head-mean -> out[Nn,128].
// concat=1: out[Nn,512] (+alpha to aout).
// ---------------------------------------------------------------------------
__global__ __launch_bounds__(256) void gat_agg(const int* __restrict__ rowptr,
                                               const int* __restrict__ csr_src,
                                               const int* __restrict__ csr_eid,
                                               const float4* __restrict__ ssrc,
                                               const float4* __restrict__ sdst,
                                               const unsigned short* __restrict__ hb,
                                               float* __restrict__ out,
                                               float4* __restrict__ aout,
                                               int Nn, int concat) {
    __shared__ float alds[4][64][4];   // per-wave alpha slab (wave-private)
    const int lane = threadIdx.x & 63;
    const int w = threadIdx.x >> 6;
    const int d = blockIdx.x * 4 + w;
    if (d >= Nn) return;
    const int beg = rowptr[d], end = rowptr[d + 1];
    const float4 sd = sdst[d];
    const float NINF = -__builtin_huge_valf();

    // per-head running max over incoming edges
    float4 m = make_float4(NINF, NINF, NINF, NINF);
    for (int i = beg + lane; i < end; i += 64) {
        float4 ev = lrelu4(add4(ssrc[csr_src[i]], sd));
        m.x = fmaxf(m.x, ev.x); m.y = fmaxf(m.y, ev.y);
        m.z = fmaxf(m.z, ev.z); m.w = fmaxf(m.w, ev.w);
    }
    for (int o = 32; o; o >>= 1) {
        m.x = fmaxf(m.x, __shfl_xor(m.x, o));
        m.y = fmaxf(m.y, __shfl_xor(m.y, o));
        m.z = fmaxf(m.z, __shfl_xor(m.z, o));
        m.w = fmaxf(m.w, __shfl_xor(m.w, o));
    }

    // denominator
    float4 den = make_float4(0.f, 0.f, 0.f, 0.f);
    for (int i = beg + lane; i < end; i += 64) {
        float4 ev = lrelu4(add4(ssrc[csr_src[i]], sd));
        den.x += __expf(ev.x - m.x); den.y += __expf(ev.y - m.y);
        den.z += __expf(ev.z - m.z); den.w += __expf(ev.w - m.w);
    }
    for (int o = 32; o; o >>= 1) {
        den.x += __shfl_xor(den.x, o);
        den.y += __shfl_xor(den.y, o);
        den.z += __shfl_xor(den.z, o);
        den.w += __shfl_xor(den.w, o);
    }
    float4 inv;
    inv.x = 1.f / den.x; inv.y = 1.f / den.y;
    inv.z = 1.f / den.z; inv.w = 1.f / den.w;

    // aggregate: lane owns channels [lane*8, lane*8+8); head = lane>>4
    const int head = lane >> 4;
    float acc[8] = {};
    for (int chunk = beg; chunk < end; chunk += 64) {
        const int n = min(64, end - chunk);
        if (lane < n) {
            int i = chunk + lane;
            float4 ev = lrelu4(add4(ssrc[csr_src[i]], sd));
            float4 a4;
            a4.x = __expf(ev.x - m.x) * inv.x;
            a4.y = __expf(ev.y - m.y) * inv.y;
            a4.z = __expf(ev.z - m.z) * inv.z;
            a4.w = __expf(ev.w - m.w) * inv.w;
            alds[w][lane][0] = a4.x; alds[w][lane][1] = a4.y;
            alds[w][lane][2] = a4.z; alds[w][lane][3] = a4.w;
            if (aout != nullptr) aout[csr_eid[i]] = a4;
        }
        // wave-private LDS: in-order per-wave DS ops, no barrier needed
        for (int j = 0; j < n; ++j) {
            int s = csr_src[chunk + j];
            float a = alds[w][j][head];
            uint4 q = *(const uint4*)(hb + (size_t)s * 512 + lane * 8);
            acc[0] += a * __uint_as_float(q.x << 16);
            acc[1] += a * __uint_as_float(q.x & 0xFFFF0000u);
            acc[2] += a * __uint_as_float(q.y << 16);
            acc[3] += a * __uint_as_float(q.y & 0xFFFF0000u);
            acc[4] += a * __uint_as_float(q.z << 16);
            acc[5] += a * __uint_as_float(q.z & 0xFFFF0000u);
            acc[6] += a * __uint_as_float(q.w << 16);
            acc[7] += a * __uint_as_float(q.w & 0xFFFF0000u);
        }
    }

    if (concat) {
        float4* orow = (float4*)(out + (size_t)d * 512 + lane * 8);
        orow[0] = make_float4(acc[0], acc[1], acc[2], acc[3]);
        orow[1] = make_float4(acc[4], acc[5], acc[6], acc[7]);
    } else {
        // head-mean: lanes {l, l^16, l^32, l^48} hold same within-head channels
#pragma unroll
        for (int k = 0; k < 8; k++) acc[k] += __shfl_xor(acc[k], 16);
#pragma unroll
        for (int k = 0; k < 8; k++) acc[k] += __shfl_xor(acc[k], 32);
        if (lane < 16) {
            float4* orow = (float4*)(out + (size_t)d * 128 + lane * 8);
            orow[0] = make_float4(0.25f * acc[0], 0.25f * acc[1], 0.25f * acc[2], 0.25f * acc[3]);
            orow[1] = make_float4(0.25f * acc[4], 0.25f * acc[5], 0.25f * acc[6], 0.25f * acc[7]);
        }
    }
}

// x = lrelu(LN(x + b1)) per node row of 128; one wave per node.
__global__ __launch_bounds__(256) void ln_lrelu(float* __restrict__ hbuf,
                                                const float* __restrict__ b1,
                                                const float* __restrict__ gg,
                                                const float* __restrict__ bb, int Nn) {
    int w = threadIdx.x >> 6, l = threadIdx.x & 63;
    int n = blockIdx.x * 4 + w;
    if (n >= Nn) return;
    float* row = hbuf + (size_t)n * 128;
    float x0 = row[l] + b1[l], x1 = row[l + 64] + b1[l + 64];
    float s = x0 + x1;
    for (int o = 32; o; o >>= 1) s += __shfl_down(s, o);
    s = __shfl(s, 0);
    float mu = s * (1.f / 128.f);
    float d0 = x0 - mu, d1 = x1 - mu;
    float v = d0 * d0 + d1 * d1;
    for (int o = 32; o; o >>= 1) v += __shfl_down(v, o);
    v = __shfl(v, 0);
    float r = rsqrtf(v * (1.f / 128.f) + 1e-5f);
    float y0 = gg[l] * d0 * r + bb[l];
    float y1 = gg[l + 64] * d1 * r + bb[l + 64];
    row[l]      = lrelu(y0);
    row[l + 64] = lrelu(y1);
}

// pooled[g,c] += sum over nodes of lrelu(out2[n,c]+b2[c]); batch is sorted.
__global__ __launch_bounds__(512) void pool_k(const float* __restrict__ out2,
                                              const float* __restrict__ b2,
                                              const int* __restrict__ batch,
                                              float* __restrict__ pooled, int Nn) {
    int c = threadIdx.x;
    int n0 = blockIdx.x * 64, n1 = min(n0 + 64, Nn);
    if (n0 >= Nn) return;
    float bc = b2[c];
    int g = batch[n0];
    float acc = 0.f;
    for (int n = n0; n < n1; ++n) {
        int bg = batch[n];
        if (bg != g) { atomicAdd(&pooled[g * 512 + c], acc); acc = 0.f; g = bg; }
        float v = out2[(size_t)n * 512 + c] + bc;
        acc += lrelu(v);
    }
    atomicAdd(&pooled[g * 512 + c], acc);
}

// batch is sorted: cnt[g] = lower_bound(g+1) - lower_bound(g). One block, no atomics.
__global__ __launch_bounds__(64) void count_sorted_k(const int* __restrict__ batch,
                                                     float* __restrict__ cnt, int Nn, int G) {
    int g = threadIdx.x;
    if (g >= G) return;
    int lo = 0, hi = Nn;
    while (lo < hi) { int mid = (lo + hi) >> 1; if (batch[mid] < g) lo = mid + 1; else hi = mid; }
    int a = lo;
    lo = 0; hi = Nn;
    while (lo < hi) { int mid = (lo + hi) >> 1; if (batch[mid] < g + 1) lo = mid + 1; else hi = mid; }
    cnt[g] = (float)(lo - a);
}

// ---------------------------------------------------------------------------
// MLP head (G=64 rows).
// ---------------------------------------------------------------------------
__device__ __forceinline__ float block_sum(float v, volatile float* sbuf, int tid, int nw) {
    for (int o = 32; o; o >>= 1) v += __shfl_down(v, o);
    if ((tid & 63) == 0) sbuf[tid >> 6] = v;
    __syncthreads();
    if (tid == 0) { float r = 0.f; for (int i = 0; i < nw; i++) r += sbuf[i]; sbuf[0] = r; }
    __syncthreads();
    float r = sbuf[0];
    __syncthreads();
    return r;
}

__global__ __launch_bounds__(128) void lin0_k(const float* __restrict__ pooled,
                                              const float* __restrict__ cnt,
                                              const float* __restrict__ W,
                                              const float* __restrict__ b,
                                              float* __restrict__ z0) {
    int g = blockIdx.x, j = threadIdx.x;
    float inv = 1.f / fmaxf(cnt[g], 1.f);
    float acc = 0.f;
    for (int k = 0; k < 512; k++) acc += pooled[g * 512 + k] * W[k * 128 + j];
    z0[g * 128 + j] = acc * inv + b[j];
}

__global__ __launch_bounds__(256) void lin1_k(const float* __restrict__ z0,
                                              const float* __restrict__ W,
                                              const float* __restrict__ b,
                                              const float* __restrict__ gw,
                                              const float* __restrict__ gb,
                                              float* __restrict__ z1) {
    __shared__ float sbuf[8];
    int g = blockIdx.x, j = threadIdx.x;
    float acc = b[j];
    for (int k = 0; k < 128; k++) acc += z0[g * 128 + k] * W[k * 256 + j];
    float mu = block_sum(acc, sbuf, j, 4) * (1.f / 256.f);
    float d = acc - mu;
    float var = block_sum(d * d, sbuf, j, 4) * (1.f / 256.f);
    float y = gw[j] * d * rsqrtf(var + 1e-5f) + gb[j];
    z1[g * 256 + j] = fmaxf(y, 0.f);
}

__global__ __launch_bounds__(128) void lin2_k(const float* __restrict__ z1,
                                              const float* __restrict__ W,
                                              const float* __restrict__ b,
                                              const float* __restrict__ gw,
                                              const float* __restrict__ gb,
                                              float* __restrict__ z2) {
    __shared__ float sbuf[8];
    int g = blockIdx.x, j = threadIdx.x;
    float acc = b[j];
    for (int k = 0; k < 256; k++) acc += z1[g * 256 + k] * W[k * 128 + j];
    float mu = block_sum(acc, sbuf, j, 2) * (1.f / 128.f);
    float d = acc - mu;
    float var = block_sum(d * d, sbuf, j, 2) * (1.f / 128.f);
    float y = gw[j] * d * rsqrtf(var + 1e-5f) + gb[j];
    z2[g * 128 + j] = fmaxf(y, 0.f);
}

__global__ __launch_bounds__(64) void lin3_k(const float* __restrict__ z2,
                                             const float* __restrict__ W,
                                             const float* __restrict__ b,
                                             float* __restrict__ probs) {
    int g = blockIdx.x, l = threadIdx.x;
    float p0 = 0.f, p1 = 0.f;
    for (int k = l; k < 128; k += 64) {
        float z = z2[g * 128 + k];
        p0 += z * W[k * 2 + 0];
        p1 += z * W[k * 2 + 1];
    }
    for (int o = 32; o; o >>= 1) { p0 += __shfl_down(p0, o); p1 += __shfl_down(p1, o); }
    if (l == 0) {
        p0 += b[0]; p1 += b[1];
        float mx = fmaxf(p0, p1);
        float e0 = __expf(p0 - mx), e1 = __expf(p1 - mx);
        float s = e0 + e1;
        probs[g * 2 + 0] = e0 / s;
        probs[g * 2 + 1] = e1 / s;
    }
}

// ---------------------------------------------------------------------------
extern "C" void kernel_launch(void* const* d_in, const int* in_sizes, int n_in,
                              void* d_out, int out_size, void* d_ws, size_t ws_size,
                              hipStream_t stream) {
    const float* x    = (const float*)d_in[0];
    const int*   ei   = (const int*)d_in[1];
    const int*   batch= (const int*)d_in[2];
    const float* W1   = (const float*)d_in[3];
    const float* as1  = (const float*)d_in[4];
    const float* ad1  = (const float*)d_in[5];
    const float* b1   = (const float*)d_in[6];
    const float* g_ln = (const float*)d_in[7];
    const float* b_ln = (const float*)d_in[8];
    const float* W2   = (const float*)d_in[9];
    const float* as2  = (const float*)d_in[10];
    const float* ad2  = (const float*)d_in[11];
    const float* b2   = (const float*)d_in[12];
    const float* Wl0  = (const float*)d_in[13];
    const float* bl0  = (const float*)d_in[14];
    const float* Ws1  = (const float*)d_in[15];
    const float* bs1  = (const float*)d_in[16];
    const float* g1   = (const float*)d_in[17];
    const float* bb1  = (const float*)d_in[18];
    const float* Ws2  = (const float*)d_in[19];
    const float* bs2  = (const float*)d_in[20];
    const float* g2   = (const float*)d_in[21];
    const float* bb2  = (const float*)d_in[22];
    const float* Ws3  = (const float*)d_in[23];
    const float* bs3  = (const float*)d_in[24];
    (void)n_in; (void)out_size; (void)ws_size;

    const int Nn = in_sizes[0] / 128;   // 30000
    const int E  = in_sizes[1] / 2;     // 480000
    const int ET = E + Nn;              // 510000
    const int G  = 64;

    // ---- workspace layout ----
    char* ws = (char*)d_ws;
    size_t off = 0;
    auto alloc = [&](size_t bytes) { void* p = ws + off; off += (bytes + 255) & ~(size_t)255; return p; };
    float* h_a    = (float*)alloc((size_t)Nn * 512 * 4);   // h1, later h2 (fp32)
    unsigned short* hb = (unsigned short*)alloc((size_t)Nn * 512 * 2); // bf16 copy
    float* hln    = (float*)alloc((size_t)Nn * 128 * 4);   // layer1 out -> LN in place
    float* out2   = (float*)alloc((size_t)Nn * 512 * 4);
    float* pooled = (float*)alloc((size_t)G * 512 * 4);
    float* cnt    = (float*)alloc((size_t)G * 4);
    float* z0     = (float*)alloc((size_t)G * 128 * 4);
    float* z1     = (float*)alloc((size_t)G * 256 * 4);
    float* z2     = (float*)alloc((size_t)G * 128 * 4);
    float* ssrc   = (float*)alloc((size_t)Nn * 4 * 4);
    float* sdst   = (float*)alloc((size_t)Nn * 4 * 4);
    int*   deg    = (int*)alloc((size_t)Nn * 4);
    int*   rowptr = (int*)alloc((size_t)(Nn + 1) * 4);
    int*   cursor = (int*)alloc((size_t)Nn * 4);
    int*   csr_src= (int*)alloc((size_t)ET * 4);
    int*   csr_eid= (int*)alloc((size_t)ET * 4);

    float* probs = (float*)d_out;
    float* aout  = (float*)d_out + 128;   // alpha [ET,4]

    // ---- init (ws poisoned 0xAA every call) ----
    hipMemsetAsync(deg, 0, (size_t)Nn * 4, stream);
    hipMemsetAsync(pooled, 0, (size_t)G * 512 * 4, stream);

    const int eblks = (ET + 255) / 256;
    dim3 ggrid((Nn + 63) / 64, 4);
    const int ablks = (Nn + 3) / 4;

    // ---- CSR build (dst segments shared by both layers) ----
    hist_k<<<eblks, 256, 0, stream>>>(ei, E, ET, deg);
    scan_k<<<1, 1024, 0, stream>>>(deg, rowptr, cursor, Nn);
    fill_csr_k<<<eblks, 256, 0, stream>>>(ei, E, ET, cursor, csr_src, csr_eid);

    // ---- layer 1 ----
    gemm128<<<ggrid, 256, 0, stream>>>(x, W1, h_a, hb, Nn, 512);
    heads_dot<<<Nn, 256, 0, stream>>>(h_a, as1, ad1, ssrc, sdst);
    gat_agg<<<ablks, 256, 0, stream>>>(rowptr, csr_src, csr_eid,
                                       (const float4*)ssrc, (const float4*)sdst,
                                       hb, hln, nullptr, Nn, 0);
    ln_lrelu<<<ablks, 256, 0, stream>>>(hln, b1, g_ln, b_ln, Nn);

    // ---- layer 2 ----
    gemm128<<<ggrid, 256, 0, stream>>>(hln, W2, h_a, hb, Nn, 512);
    heads_dot<<<Nn, 256, 0, stream>>>(h_a, as2, ad2, ssrc, sdst);
    gat_agg<<<ablks, 256, 0, stream>>>(rowptr, csr_src, csr_eid,
                                       (const float4*)ssrc, (const float4*)sdst,
                                       hb, out2, (float4*)aout, Nn, 1);

    // ---- pool + MLP head ----
    pool_k<<<(Nn + 63) / 64, 512, 0, stream>>>(out2, b2, batch, pooled, Nn);
    count_sorted_k<<<1, 64, 0, stream>>>(batch, cnt, Nn, G);
    lin0_k<<<G, 128, 0, stream>>>(pooled, cnt, Wl0, bl0, z0);
    lin1_k<<<G, 256, 0, stream>>>(z0, Ws1, bs1, g1, bb1, z1);
    lin2_k<<<G, 128, 0, stream>>>(z1, Ws2, bs2, g2, bb2, z2);
    lin3_k<<<G, 64, 0, stream>>>(z2, Ws3, bs3, probs);
}

// Round 11
// 601.005 us; speedup vs baseline: 3.7028x; 1.0765x over previous
//
#include <hip/hip_runtime.h>
#include <cstdint>
#include <cstddef>

// ---------------------------------------------------------------------------
// GAT forward: N=30000, E=480000 (+N self loops), ATOM=HID=128, H=4, OUT=256
// Outputs: probs [64,2] then alpha2 [E+N, 4], flat in d_out.
// R2: CSR-by-destination + per-wave softmax/aggregate (no edge atomics).
// R7: sorted-batch count; lane-parallel alpha into per-wave LDS.
// R8: bf16 gather copy (halves gather traffic); 2 col-tiles per A-tile.
// R10: heads_dot fused into gemm epilogue (block = one head; fp32 acc dots,
//      xor-reduce, no atomics; fp32 C never written). ln_lrelu fused into
//      gat_agg concat=0 epilogue (LN via 16-lane xor-reduces).
// ---------------------------------------------------------------------------

__device__ __forceinline__ float lrelu(float v) { return v >= 0.f ? v : 0.2f * v; }

__device__ __forceinline__ float4 lrelu4(float4 v) {
    return make_float4(lrelu(v.x), lrelu(v.y), lrelu(v.z), lrelu(v.w));
}
__device__ __forceinline__ float4 add4(float4 a, float4 b) {
    return make_float4(a.x + b.x, a.y + b.y, a.z + b.z, a.w + b.w);
}

// round-to-nearest-even float -> bf16 bits
__device__ __forceinline__ unsigned short f2bf(float x) {
    unsigned int u = __float_as_uint(x);
    u += 0x7FFFu + ((u >> 16) & 1u);
    return (unsigned short)(u >> 16);
}

// ---------------------------------------------------------------------------
// hb[M,512](bf16) = A[M,128] @ B[128,512]; fused per-head score dots:
// ssrc[n,head] = sum_c h[n,head,c]*a_s[head,c] (head = blockIdx.y), same sdst.
// 64-row tile; TWO 64-col tiles per A-tile load. fp32 C is never stored.
// ---------------------------------------------------------------------------
__global__ __launch_bounds__(256) void gemm_fused(const float* __restrict__ A,
                                                  const float* __restrict__ B,
                                                  unsigned short* __restrict__ Cb,
                                                  const float* __restrict__ a_s,
                                                  const float* __restrict__ a_d,
                                                  float* __restrict__ ssrc,
                                                  float* __restrict__ sdst,
                                                  int M, int N) {
    __shared__ float As[64][132];
    __shared__ float Bs[128][64];
    const int tid  = threadIdx.x;
    const int row0 = blockIdx.x * 64;
    const int by   = blockIdx.y;            // == head index (128 cols/head)
    const int colbase = by * 128;

#pragma unroll
    for (int i = 0; i < 8; i++) {                // A tile: 64 rows x 128 cols
        int idx = tid + i * 256;
        int r = idx >> 5, c4 = idx & 31;
        int gr = row0 + r;
        float4 v = make_float4(0.f, 0.f, 0.f, 0.f);
        if (gr < M) v = *(const float4*)&A[(size_t)gr * 128 + c4 * 4];
        *(float4*)&As[r][c4 * 4] = v;
    }

    const int tx = tid & 15, ty = tid >> 4;
    float ps[4] = {}, pd[4] = {};                // per-row score partials

    for (int half = 0; half < 2; ++half) {
        const int col0 = colbase + half * 64;
        if (half) __syncthreads();               // compute(half0) done before Bs overwrite
#pragma unroll
        for (int i = 0; i < 8; i++) {            // B tile: 128 rows x 64 cols
            int idx = tid + i * 256;
            int r = idx >> 4, c4 = idx & 15;
            *(float4*)&Bs[r][c4 * 4] = *(const float4*)&B[(size_t)r * N + col0 + c4 * 4];
        }
        __syncthreads();

        float acc[4][4] = {};
#pragma unroll 2
        for (int k = 0; k < 128; k += 4) {
            float4 a[4], b[4];
#pragma unroll
            for (int i = 0; i < 4; i++) a[i] = *(const float4*)&As[ty * 4 + i][k];
#pragma unroll
            for (int j = 0; j < 4; j++) b[j] = *(const float4*)&Bs[k + j][tx * 4];
#pragma unroll
            for (int i = 0; i < 4; i++) {
                acc[i][0] += a[i].x * b[0].x + a[i].y * b[1].x + a[i].z * b[2].x + a[i].w * b[3].x;
                acc[i][1] += a[i].x * b[0].y + a[i].y * b[1].y + a[i].z * b[2].y + a[i].w * b[3].y;
                acc[i][2] += a[i].x * b[0].z + a[i].y * b[1].z + a[i].z * b[2].z + a[i].w * b[3].z;
                acc[i][3] += a[i].x * b[0].w + a[i].y * b[1].w + a[i].z * b[2].w + a[i].w * b[3].w;
            }
        }

        // score partials over this half's 4 cols (within-head col = half*64+tx*4+j)
        const int hc = half * 64 + tx * 4;
        float4 asv = *(const float4*)&a_s[by * 128 + hc];
        float4 adv = *(const float4*)&a_d[by * 128 + hc];
#pragma unroll
        for (int i = 0; i < 4; i++) {
            ps[i] += acc[i][0] * asv.x + acc[i][1] * asv.y + acc[i][2] * asv.z + acc[i][3] * asv.w;
            pd[i] += acc[i][0] * adv.x + acc[i][1] * adv.y + acc[i][2] * adv.z + acc[i][3] * adv.w;
        }

#pragma unroll
        for (int i = 0; i < 4; i++) {
            int gr = row0 + ty * 4 + i;
            if (gr < M) {
                ushort4 bv;
                bv.x = f2bf(acc[i][0]); bv.y = f2bf(acc[i][1]);
                bv.z = f2bf(acc[i][2]); bv.w = f2bf(acc[i][3]);
                *(ushort4*)&Cb[(size_t)gr * N + col0 + tx * 4] = bv;
            }
        }
    }

    // reduce partials across the 16 tx lanes (same ty group)
#pragma unroll
    for (int o = 1; o <= 8; o <<= 1) {
#pragma unroll
        for (int i = 0; i < 4; i++) {
            ps[i] += __shfl_xor(ps[i], o);
            pd[i] += __shfl_xor(pd[i], o);
        }
    }
    if (tx == 0) {
#pragma unroll
        for (int i = 0; i < 4; i++) {
            int gr = row0 + ty * 4 + i;
            if (gr < M) { ssrc[gr * 4 + by] = ps[i]; sdst[gr * 4 + by] = pd[i]; }
        }
    }
}

// ---------------------------------------------------------------------------
// CSR build: histogram of dst -> prefix scan -> fill (csr_src, csr_eid).
// ---------------------------------------------------------------------------
__global__ void hist_k(const int* __restrict__ ei, int E, int ET, int* __restrict__ deg) {
    int e = blockIdx.x * 256 + threadIdx.x;
    if (e >= ET) return;
    int d = (e < E) ? ei[E + e] : e - E;
    atomicAdd(&deg[d], 1);
}

// Single-block exclusive scan over deg[Nn] -> rowptr[Nn+1], cursor[Nn].
__global__ __launch_bounds__(1024) void scan_k(const int* __restrict__ deg,
                                               int* __restrict__ rowptr,
                                               int* __restrict__ cursor, int Nn) {
    __shared__ int part[1024];
    int t = threadIdx.x;
    int per = (Nn + 1023) / 1024;
    int b0 = t * per, b1 = min(b0 + per, Nn);
    int s = 0;
    for (int i = b0; i < b1; i++) s += deg[i];
    part[t] = s;
    __syncthreads();
    for (int o = 1; o < 1024; o <<= 1) {
        int x = (t >= o) ? part[t - o] : 0;
        __syncthreads();
        part[t] += x;
        __syncthreads();
    }
    int off = part[t] - s;   // exclusive prefix for this thread's range
    for (int i = b0; i < b1; i++) {
        rowptr[i] = off; cursor[i] = off; off += deg[i];
    }
    if (t == 1023) rowptr[Nn] = part[1023];
}

__global__ void fill_csr_k(const int* __restrict__ ei, int E, int ET,
                           int* __restrict__ cursor,
                           int* __restrict__ csr_src, int* __restrict__ csr_eid) {
    int e = blockIdx.x * 256 + threadIdx.x;
    if (e >= ET) return;
    int s, d;
    if (e < E) { s = ei[e]; d = ei[E + e]; } else { s = d = e - E; }
    int pos = atomicAdd(&cursor[d], 1);
    csr_src[pos] = s;
    csr_eid[pos] = e;
}

// ---------------------------------------------------------------------------
// Fused per-destination softmax + aggregate. One wave per dst (4 dst/block).
// Gathers bf16 hb. concat=0: head-mean + b1 + LayerNorm + lrelu -> out[Nn,128].
// concat=1: out[Nn,512] raw (+alpha to aout).
// ---------------------------------------------------------------------------
__global__ __launch_bounds__(256) void gat_agg(const int* __restrict__ rowptr,
                                               const int* __restrict__ csr_src,
                                               const int* __restrict__ csr_eid,
                                               const float4* __restrict__ ssrc,
                                               const float4* __restrict__ sdst,
                                               const unsigned short* __restrict__ hb,
                                               float* __restrict__ out,
                                               float4* __restrict__ aout,
                                               const float* __restrict__ b1,
                                               const float* __restrict__ gln,
                                               const float* __restrict__ bln,
                                               int Nn, int concat) {
    __shared__ float alds[4][64][4];   // per-wave alpha slab (wave-private)
    const int lane = threadIdx.x & 63;
    const int w = threadIdx.x >> 6;
    const int d = blockIdx.x * 4 + w;
    if (d >= Nn) return;
    const int beg = rowptr[d], end = rowptr[d + 1];
    const float4 sd = sdst[d];
    const float NINF = -__builtin_huge_valf();

    // per-head running max over incoming edges
    float4 m = make_float4(NINF, NINF, NINF, NINF);
    for (int i = beg + lane; i < end; i += 64) {
        float4 ev = lrelu4(add4(ssrc[csr_src[i]], sd));
        m.x = fmaxf(m.x, ev.x); m.y = fmaxf(m.y, ev.y);
        m.z = fmaxf(m.z, ev.z); m.w = fmaxf(m.w, ev.w);
    }
    for (int o = 32; o; o >>= 1) {
        m.x = fmaxf(m.x, __shfl_xor(m.x, o));
        m.y = fmaxf(m.y, __shfl_xor(m.y, o));
        m.z = fmaxf(m.z, __shfl_xor(m.z, o));
        m.w = fmaxf(m.w, __shfl_xor(m.w, o));
    }

    // denominator
    float4 den = make_float4(0.f, 0.f, 0.f, 0.f);
    for (int i = beg + lane; i < end; i += 64) {
        float4 ev = lrelu4(add4(ssrc[csr_src[i]], sd));
        den.x += __expf(ev.x - m.x); den.y += __expf(ev.y - m.y);
        den.z += __expf(ev.z - m.z); den.w += __expf(ev.w - m.w);
    }
    for (int o = 32; o; o >>= 1) {
        den.x += __shfl_xor(den.x, o);
        den.y += __shfl_xor(den.y, o);
        den.z += __shfl_xor(den.z, o);
        den.w += __shfl_xor(den.w, o);
    }
    float4 inv;
    inv.x = 1.f / den.x; inv.y = 1.f / den.y;
    inv.z = 1.f / den.z; inv.w = 1.f / den.w;

    // aggregate: lane owns channels [lane*8, lane*8+8); head = lane>>4
    const int head = lane >> 4;
    float acc[8] = {};
    for (int chunk = beg; chunk < end; chunk += 64) {
        const int n = min(64, end - chunk);
        if (lane < n) {
            int i = chunk + lane;
            float4 ev = lrelu4(add4(ssrc[csr_src[i]], sd));
            float4 a4;
            a4.x = __expf(ev.x - m.x) * inv.x;
            a4.y = __expf(ev.y - m.y) * inv.y;
            a4.z = __expf(ev.z - m.z) * inv.z;
            a4.w = __expf(ev.w - m.w) * inv.w;
            alds[w][lane][0] = a4.x; alds[w][lane][1] = a4.y;
            alds[w][lane][2] = a4.z; alds[w][lane][3] = a4.w;
            if (aout != nullptr) aout[csr_eid[i]] = a4;
        }
        // wave-private LDS: in-order per-wave DS ops, no barrier needed
        for (int j = 0; j < n; ++j) {
            int s = csr_src[chunk + j];
            float a = alds[w][j][head];
            uint4 q = *(const uint4*)(hb + (size_t)s * 512 + lane * 8);
            acc[0] += a * __uint_as_float(q.x << 16);
            acc[1] += a * __uint_as_float(q.x & 0xFFFF0000u);
            acc[2] += a * __uint_as_float(q.y << 16);
            acc[3] += a * __uint_as_float(q.y & 0xFFFF0000u);
            acc[4] += a * __uint_as_float(q.z << 16);
            acc[5] += a * __uint_as_float(q.z & 0xFFFF0000u);
            acc[6] += a * __uint_as_float(q.w << 16);
            acc[7] += a * __uint_as_float(q.w & 0xFFFF0000u);
        }
    }

    if (concat) {
        float4* orow = (float4*)(out + (size_t)d * 512 + lane * 8);
        orow[0] = make_float4(acc[0], acc[1], acc[2], acc[3]);
        orow[1] = make_float4(acc[4], acc[5], acc[6], acc[7]);
    } else {
        // head-mean: groups {l, l^16, l^32, l^48} hold the same within-head channels
#pragma unroll
        for (int k = 0; k < 8; k++) acc[k] += __shfl_xor(acc[k], 16);
#pragma unroll
        for (int k = 0; k < 8; k++) acc[k] += __shfl_xor(acc[k], 32);
        // fused: x = mean + b1; LayerNorm over 128 channels; lrelu
        const int c0 = (lane & 15) * 8;
        float val[8];
        float s = 0.f;
#pragma unroll
        for (int k = 0; k < 8; k++) { val[k] = 0.25f * acc[k] + b1[c0 + k]; s += val[k]; }
#pragma unroll
        for (int o = 1; o <= 8; o <<= 1) s += __shfl_xor(s, o);
        float mu = s * (1.f / 128.f);
        float v = 0.f;
#pragma unroll
        for (int k = 0; k < 8; k++) { float dk = val[k] - mu; v += dk * dk; }
#pragma unroll
        for (int o = 1; o <= 8; o <<= 1) v += __shfl_xor(v, o);
        float r = rsqrtf(v * (1.f / 128.f) + 1e-5f);
        if (lane < 16) {
            float y[8];
#pragma unroll
            for (int k = 0; k < 8; k++)
                y[k] = lrelu(gln[c0 + k] * (val[k] - mu) * r + bln[c0 + k]);
            float4* orow = (float4*)(out + (size_t)d * 128 + c0);
            orow[0] = make_float4(y[0], y[1], y[2], y[3]);
            orow[1] = make_float4(y[4], y[5], y[6], y[7]);
        }
    }
}

// pooled[g,c] += sum over nodes of lrelu(out2[n,c]+b2[c]); batch is sorted.
__global__ __launch_bounds__(512) void pool_k(const float* __restrict__ out2,
                                              const float* __restrict__ b2,
                                              const int* __restrict__ batch,
                                              float* __restrict__ pooled, int Nn) {
    int c = threadIdx.x;
    int n0 = blockIdx.x * 64, n1 = min(n0 + 64, Nn);
    if (n0 >= Nn) return;
    float bc = b2[c];
    int g = batch[n0];
    float acc = 0.f;
    for (int n = n0; n < n1; ++n) {
        int bg = batch[n];
        if (bg != g) { atomicAdd(&pooled[g * 512 + c], acc); acc = 0.f; g = bg; }
        float v = out2[(size_t)n * 512 + c] + bc;
        acc += lrelu(v);
    }
    atomicAdd(&pooled[g * 512 + c], acc);
}

// batch is sorted: cnt[g] = lower_bound(g+1) - lower_bound(g). One block, no atomics.
__global__ __launch_bounds__(64) void count_sorted_k(const int* __restrict__ batch,
                                                     float* __restrict__ cnt, int Nn, int G) {
    int g = threadIdx.x;
    if (g >= G) return;
    int lo = 0, hi = Nn;
    while (lo < hi) { int mid = (lo + hi) >> 1; if (batch[mid] < g) lo = mid + 1; else hi = mid; }
    int a = lo;
    lo = 0; hi = Nn;
    while (lo < hi) { int mid = (lo + hi) >> 1; if (batch[mid] < g + 1) lo = mid + 1; else hi = mid; }
    cnt[g] = (float)(lo - a);
}

// ---------------------------------------------------------------------------
// MLP head (G=64 rows).
// ---------------------------------------------------------------------------
__device__ __forceinline__ float block_sum(float v, volatile float* sbuf, int tid, int nw) {
    for (int o = 32; o; o >>= 1) v += __shfl_down(v, o);
    if ((tid & 63) == 0) sbuf[tid >> 6] = v;
    __syncthreads();
    if (tid == 0) { float r = 0.f; for (int i = 0; i < nw; i++) r += sbuf[i]; sbuf[0] = r; }
    __syncthreads();
    float r = sbuf[0];
    __syncthreads();
    return r;
}

__global__ __launch_bounds__(128) void lin0_k(const float* __restrict__ pooled,
                                              const float* __restrict__ cnt,
                                              const float* __restrict__ W,
                                              const float* __restrict__ b,
                                              float* __restrict__ z0) {
    int g = blockIdx.x, j = threadIdx.x;
    float inv = 1.f / fmaxf(cnt[g], 1.f);
    float acc = 0.f;
    for (int k = 0; k < 512; k++) acc += pooled[g * 512 + k] * W[k * 128 + j];
    z0[g * 128 + j] = acc * inv + b[j];
}

__global__ __launch_bounds__(256) void lin1_k(const float* __restrict__ z0,
                                              const float* __restrict__ W,
                                              const float* __restrict__ b,
                                              const float* __restrict__ gw,
                                              const float* __restrict__ gb,
                                              float* __restrict__ z1) {
    __shared__ float sbuf[8];
    int g = blockIdx.x, j = threadIdx.x;
    float acc = b[j];
    for (int k = 0; k < 128; k++) acc += z0[g * 128 + k] * W[k * 256 + j];
    float mu = block_sum(acc, sbuf, j, 4) * (1.f / 256.f);
    float d = acc - mu;
    float var = block_sum(d * d, sbuf, j, 4) * (1.f / 256.f);
    float y = gw[j] * d * rsqrtf(var + 1e-5f) + gb[j];
    z1[g * 256 + j] = fmaxf(y, 0.f);
}

__global__ __launch_bounds__(128) void lin2_k(const float* __restrict__ z1,
                                              const float* __restrict__ W,
                                              const float* __restrict__ b,
                                              const float* __restrict__ gw,
                                              const float* __restrict__ gb,
                                              float* __restrict__ z2) {
    __shared__ float sbuf[8];
    int g = blockIdx.x, j = threadIdx.x;
    float acc = b[j];
    for (int k = 0; k < 256; k++) acc += z1[g * 256 + k] * W[k * 128 + j];
    float mu = block_sum(acc, sbuf, j, 2) * (1.f / 128.f);
    float d = acc - mu;
    float var = block_sum(d * d, sbuf, j, 2) * (1.f / 128.f);
    float y = gw[j] * d * rsqrtf(var + 1e-5f) + gb[j];
    z2[g * 128 + j] = fmaxf(y, 0.f);
}

__global__ __launch_bounds__(64) void lin3_k(const float* __restrict__ z2,
                                             const float* __restrict__ W,
                                             const float* __restrict__ b,
                                             float* __restrict__ probs) {
    int g = blockIdx.x, l = threadIdx.x;
    float p0 = 0.f, p1 = 0.f;
    for (int k = l; k < 128; k += 64) {
        float z = z2[g * 128 + k];
        p0 += z * W[k * 2 + 0];
        p1 += z * W[k * 2 + 1];
    }
    for (int o = 32; o; o >>= 1) { p0 += __shfl_down(p0, o); p1 += __shfl_down(p1, o); }
    if (l == 0) {
        p0 += b[0]; p1 += b[1];
        float mx = fmaxf(p0, p1);
        float e0 = __expf(p0 - mx), e1 = __expf(p1 - mx);
        float s = e0 + e1;
        probs[g * 2 + 0] = e0 / s;
        probs[g * 2 + 1] = e1 / s;
    }
}

// ---------------------------------------------------------------------------
extern "C" void kernel_launch(void* const* d_in, const int* in_sizes, int n_in,
                              void* d_out, int out_size, void* d_ws, size_t ws_size,
                              hipStream_t stream) {
    const float* x    = (const float*)d_in[0];
    const int*   ei   = (const int*)d_in[1];
    const int*   batch= (const int*)d_in[2];
    const float* W1   = (const float*)d_in[3];
    const float* as1  = (const float*)d_in[4];
    const float* ad1  = (const float*)d_in[5];
    const float* b1   = (const float*)d_in[6];
    const float* g_ln = (const float*)d_in[7];
    const float* b_ln = (const float*)d_in[8];
    const float* W2   = (const float*)d_in[9];
    const float* as2  = (const float*)d_in[10];
    const float* ad2  = (const float*)d_in[11];
    const float* b2   = (const float*)d_in[12];
    const float* Wl0  = (const float*)d_in[13];
    const float* bl0  = (const float*)d_in[14];
    const float* Ws1  = (const float*)d_in[15];
    const float* bs1  = (const float*)d_in[16];
    const float* g1   = (const float*)d_in[17];
    const float* bb1  = (const float*)d_in[18];
    const float* Ws2  = (const float*)d_in[19];
    const float* bs2  = (const float*)d_in[20];
    const float* g2   = (const float*)d_in[21];
    const float* bb2  = (const float*)d_in[22];
    const float* Ws3  = (const float*)d_in[23];
    const float* bs3  = (const float*)d_in[24];
    (void)n_in; (void)out_size; (void)ws_size;

    const int Nn = in_sizes[0] / 128;   // 30000
    const int E  = in_sizes[1] / 2;     // 480000
    const int ET = E + Nn;              // 510000
    const int G  = 64;

    // ---- workspace layout ----
    char* ws = (char*)d_ws;
    size_t off = 0;
    auto alloc = [&](size_t bytes) { void* p = ws + off; off += (bytes + 255) & ~(size_t)255; return p; };
    unsigned short* hb = (unsigned short*)alloc((size_t)Nn * 512 * 2); // bf16 h
    float* hln    = (float*)alloc((size_t)Nn * 128 * 4);   // layer1 out (post-LN)
    float* out2   = (float*)alloc((size_t)Nn * 512 * 4);
    float* pooled = (float*)alloc((size_t)G * 512 * 4);
    float* cnt    = (float*)alloc((size_t)G * 4);
    float* z0     = (float*)alloc((size_t)G * 128 * 4);
    float* z1     = (float*)alloc((size_t)G * 256 * 4);
    float* z2     = (float*)alloc((size_t)G * 128 * 4);
    float* ssrc   = (float*)alloc((size_t)Nn * 4 * 4);
    float* sdst   = (float*)alloc((size_t)Nn * 4 * 4);
    int*   deg    = (int*)alloc((size_t)Nn * 4);
    int*   rowptr = (int*)alloc((size_t)(Nn + 1) * 4);
    int*   cursor = (int*)alloc((size_t)Nn * 4);
    int*   csr_src= (int*)alloc((size_t)ET * 4);
    int*   csr_eid= (int*)alloc((size_t)ET * 4);

    float* probs = (float*)d_out;
    float* aout  = (float*)d_out + 128;   // alpha [ET,4]

    // ---- init (ws poisoned 0xAA every call) ----
    hipMemsetAsync(deg, 0, (size_t)Nn * 4, stream);
    hipMemsetAsync(pooled, 0, (size_t)G * 512 * 4, stream);

    const int eblks = (ET + 255) / 256;
    dim3 ggrid((Nn + 63) / 64, 4);
    const int ablks = (Nn + 3) / 4;

    // ---- CSR build (dst segments shared by both layers) ----
    hist_k<<<eblks, 256, 0, stream>>>(ei, E, ET, deg);
    scan_k<<<1, 1024, 0, stream>>>(deg, rowptr, cursor, Nn);
    fill_csr_k<<<eblks, 256, 0, stream>>>(ei, E, ET, cursor, csr_src, csr_eid);

    // ---- layer 1 ----
    gemm_fused<<<ggrid, 256, 0, stream>>>(x, W1, hb, as1, ad1, ssrc, sdst, Nn, 512);
    gat_agg<<<ablks, 256, 0, stream>>>(rowptr, csr_src, csr_eid,
                                       (const float4*)ssrc, (const float4*)sdst,
                                       hb, hln, nullptr, b1, g_ln, b_ln, Nn, 0);

    // ---- layer 2 ----
    gemm_fused<<<ggrid, 256, 0, stream>>>(hln, W2, hb, as2, ad2, ssrc, sdst, Nn, 512);
    gat_agg<<<ablks, 256, 0, stream>>>(rowptr, csr_src, csr_eid,
                                       (const float4*)ssrc, (const float4*)sdst,
                                       hb, out2, (float4*)aout, nullptr, nullptr, nullptr, Nn, 1);

    // ---- pool + MLP head ----
    pool_k<<<(Nn + 63) / 64, 512, 0, stream>>>(out2, b2, batch, pooled, Nn);
    count_sorted_k<<<1, 64, 0, stream>>>(batch, cnt, Nn, G);
    lin0_k<<<G, 128, 0, stream>>>(pooled, cnt, Wl0, bl0, z0);
    lin1_k<<<G, 256, 0, stream>>>(z0, Ws1, bs1, g1, bb1, z1);
    lin2_k<<<G, 128, 0, stream>>>(z1, Ws2, bs2, g2, bb2, z2);
    lin3_k<<<G, 64, 0, stream>>>(z2, Ws3, bs3, probs);
}

// Round 12
// 483.708 us; speedup vs baseline: 4.6007x; 1.2425x over previous
//
#include <hip/hip_runtime.h>
#include <cstdint>
#include <cstddef>

// ---------------------------------------------------------------------------
// GAT forward: N=30000, E=480000 (+N self loops), ATOM=HID=128, H=4, OUT=256
// Outputs: probs [64,2] then alpha2 [E+N, 4], flat in d_out.
// R2: CSR-by-destination + per-wave softmax/aggregate (no edge atomics).
// R7: sorted-batch count; lane-parallel alpha into per-wave LDS.
// R8: bf16 gather copy (halves gather traffic).
// R10: score dots fused into gemm epilogue (fp32 acc); LN fused into gat_agg.
// R11: GEMM -> bf16 MFMA (16x16x32), scores still from fp32 accumulator;
//      x/hln kept bf16; W pre-transposed bf16 [head][col][k]; MLP head merged
//      into one kernel (incl. count via binary search).
// ---------------------------------------------------------------------------

typedef __attribute__((ext_vector_type(8))) short bf16x8;
typedef __attribute__((ext_vector_type(4))) float f32x4;

__device__ __forceinline__ float lrelu(float v) { return v >= 0.f ? v : 0.2f * v; }

__device__ __forceinline__ float4 lrelu4(float4 v) {
    return make_float4(lrelu(v.x), lrelu(v.y), lrelu(v.z), lrelu(v.w));
}
__device__ __forceinline__ float4 add4(float4 a, float4 b) {
    return make_float4(a.x + b.x, a.y + b.y, a.z + b.z, a.w + b.w);
}

// round-to-nearest-even float -> bf16 bits
__device__ __forceinline__ unsigned short f2bf(float x) {
    unsigned int u = __float_as_uint(x);
    u += 0x7FFFu + ((u >> 16) & 1u);
    return (unsigned short)(u >> 16);
}

// ---------------------------------------------------------------------------
// fp32 -> bf16 elementwise (for x)
// ---------------------------------------------------------------------------
__global__ void cvt_bf16_k(const float* __restrict__ src,
                           unsigned short* __restrict__ dst, int n4) {
    int i = blockIdx.x * 256 + threadIdx.x;
    if (i >= n4) return;
    float4 v = *(const float4*)&src[i * 4];
    ushort4 o;
    o.x = f2bf(v.x); o.y = f2bf(v.y); o.z = f2bf(v.z); o.w = f2bf(v.w);
    *(ushort4*)&dst[i * 4] = o;
}

// W[128k][512] fp32 -> Wbt[head][128col][128k] bf16 (both layers, z picks W)
__global__ void cvt_wt_k(const float* __restrict__ W1, const float* __restrict__ W2,
                         unsigned short* __restrict__ Wt1, unsigned short* __restrict__ Wt2) {
    const float* W = blockIdx.z ? W2 : W1;
    unsigned short* Wt = blockIdx.z ? Wt2 : Wt1;
    int head = blockIdx.y;
    int idx = blockIdx.x * 256 + threadIdx.x;   // 16384 per head
    int k = idx >> 7, c = idx & 127;
    Wt[((size_t)head * 128 + c) * 128 + k] = f2bf(W[(size_t)k * 512 + head * 128 + c]);
}

// ---------------------------------------------------------------------------
// MFMA GEMM: hb[M,512](bf16) = Abf[M,128] @ W (via Wbt[head][col][k]).
// Block = 64 rows x 1 head (128 cols), 4 waves; wave w: rows w*16..+15.
// Fused score dots from fp32 accumulator -> ssrc/sdst[n,head].
// A/B fragments: lane l&15 = row/col, k = (l>>4)*8 + j (16x16x32 bf16 layout);
// D: col=l&15, row=(l>>4)*4+reg (m89-verified).
// ---------------------------------------------------------------------------
__global__ __launch_bounds__(256) void gemm_mfma(const unsigned short* __restrict__ Abf,
                                                 const unsigned short* __restrict__ Wbt,
                                                 unsigned short* __restrict__ hbout,
                                                 const float* __restrict__ a_s,
                                                 const float* __restrict__ a_d,
                                                 float* __restrict__ ssrc,
                                                 float* __restrict__ sdst, int M) {
    __shared__ unsigned short Als[64][136];    // 272 B rows: 16B-aligned, 2-way banks
    __shared__ unsigned short Bls[128][136];
    const int tid = threadIdx.x;
    const int row0 = blockIdx.x * 64;
    const int head = blockIdx.y;

    // stage A: 64 rows x 128 k, 16B chunks (1024), 4/thread
#pragma unroll
    for (int i = 0; i < 4; i++) {
        int c = tid + i * 256;
        int r = c >> 4, k0 = (c & 15) * 8;
        uint4 v = make_uint4(0, 0, 0, 0);
        int gr = row0 + r;
        if (gr < M) v = *(const uint4*)&Abf[(size_t)gr * 128 + k0];
        *(uint4*)&Als[r][k0] = v;
    }
    // stage B: Wbt[head]: 128 cols x 128 k, 16B chunks (2048), 8/thread
    const unsigned short* Wh = Wbt + (size_t)head * 128 * 128;
#pragma unroll
    for (int i = 0; i < 8; i++) {
        int c = tid + i * 256;
        int col = c >> 4, k0 = (c & 15) * 8;
        *(uint4*)&Bls[col][k0] = *(const uint4*)&Wh[col * 128 + k0];
    }
    __syncthreads();

    const int w = tid >> 6, l = tid & 63;
    const int li = l & 15, lg = l >> 4;

    f32x4 acc[8] = {};
#pragma unroll
    for (int kt = 0; kt < 4; kt++) {
        bf16x8 a = *(const bf16x8*)&Als[w * 16 + li][kt * 32 + lg * 8];
#pragma unroll
        for (int ct = 0; ct < 8; ct++) {
            bf16x8 b = *(const bf16x8*)&Bls[ct * 16 + li][kt * 32 + lg * 8];
            acc[ct] = __builtin_amdgcn_mfma_f32_16x16x32_bf16(a, b, acc[ct], 0, 0, 0);
        }
    }

    // hb writes: row = row0 + w*16 + lg*4 + r, col = head*128 + ct*16 + li
#pragma unroll
    for (int ct = 0; ct < 8; ct++) {
#pragma unroll
        for (int r = 0; r < 4; r++) {
            int gr = row0 + w * 16 + lg * 4 + r;
            if (gr < M)
                hbout[(size_t)gr * 512 + head * 128 + ct * 16 + li] = f2bf(acc[ct][r]);
        }
    }

    // fused per-head score dots from fp32 acc
    float ps[4] = {}, pd[4] = {};
#pragma unroll
    for (int ct = 0; ct < 8; ct++) {
        float as_v = a_s[head * 128 + ct * 16 + li];
        float ad_v = a_d[head * 128 + ct * 16 + li];
#pragma unroll
        for (int r = 0; r < 4; r++) { ps[r] += acc[ct][r] * as_v; pd[r] += acc[ct][r] * ad_v; }
    }
#pragma unroll
    for (int o = 1; o <= 8; o <<= 1) {
#pragma unroll
        for (int r = 0; r < 4; r++) { ps[r] += __shfl_xor(ps[r], o); pd[r] += __shfl_xor(pd[r], o); }
    }
    if (li == 0) {
#pragma unroll
        for (int r = 0; r < 4; r++) {
            int gr = row0 + w * 16 + lg * 4 + r;
            if (gr < M) { ssrc[gr * 4 + head] = ps[r]; sdst[gr * 4 + head] = pd[r]; }
        }
    }
}

// ---------------------------------------------------------------------------
// CSR build: histogram of dst -> prefix scan -> fill (csr_src, csr_eid).
// ---------------------------------------------------------------------------
__global__ void hist_k(const int* __restrict__ ei, int E, int ET, int* __restrict__ deg) {
    int e = blockIdx.x * 256 + threadIdx.x;
    if (e >= ET) return;
    int d = (e < E) ? ei[E + e] : e - E;
    atomicAdd(&deg[d], 1);
}

__global__ __launch_bounds__(1024) void scan_k(const int* __restrict__ deg,
                                               int* __restrict__ rowptr,
                                               int* __restrict__ cursor, int Nn) {
    __shared__ int part[1024];
    int t = threadIdx.x;
    int per = (Nn + 1023) / 1024;
    int b0 = t * per, b1 = min(b0 + per, Nn);
    int s = 0;
    for (int i = b0; i < b1; i++) s += deg[i];
    part[t] = s;
    __syncthreads();
    for (int o = 1; o < 1024; o <<= 1) {
        int x = (t >= o) ? part[t - o] : 0;
        __syncthreads();
        part[t] += x;
        __syncthreads();
    }
    int off = part[t] - s;
    for (int i = b0; i < b1; i++) {
        rowptr[i] = off; cursor[i] = off; off += deg[i];
    }
    if (t == 1023) rowptr[Nn] = part[1023];
}

__global__ void fill_csr_k(const int* __restrict__ ei, int E, int ET,
                           int* __restrict__ cursor,
                           int* __restrict__ csr_src, int* __restrict__ csr_eid) {
    int e = blockIdx.x * 256 + threadIdx.x;
    if (e >= ET) return;
    int s, d;
    if (e < E) { s = ei[e]; d = ei[E + e]; } else { s = d = e - E; }
    int pos = atomicAdd(&cursor[d], 1);
    csr_src[pos] = s;
    csr_eid[pos] = e;
}

// ---------------------------------------------------------------------------
// Fused per-destination softmax + aggregate. One wave per dst (4 dst/block).
// Gathers bf16 hb. concat=0: head-mean + b1 + LN + lrelu -> outb[Nn,128] bf16.
// concat=1: out[Nn,512] fp32 (+alpha to aout).
// ---------------------------------------------------------------------------
__global__ __launch_bounds__(256) void gat_agg(const int* __restrict__ rowptr,
                                               const int* __restrict__ csr_src,
                                               const int* __restrict__ csr_eid,
                                               const float4* __restrict__ ssrc,
                                               const float4* __restrict__ sdst,
                                               const unsigned short* __restrict__ hb,
                                               float* __restrict__ out,
                                               unsigned short* __restrict__ outb,
                                               float4* __restrict__ aout,
                                               const float* __restrict__ b1,
                                               const float* __restrict__ gln,
                                               const float* __restrict__ bln,
                                               int Nn, int concat) {
    __shared__ float alds[4][64][4];
    const int lane = threadIdx.x & 63;
    const int w = threadIdx.x >> 6;
    const int d = blockIdx.x * 4 + w;
    if (d >= Nn) return;
    const int beg = rowptr[d], end = rowptr[d + 1];
    const float4 sd = sdst[d];
    const float NINF = -__builtin_huge_valf();

    float4 m = make_float4(NINF, NINF, NINF, NINF);
    for (int i = beg + lane; i < end; i += 64) {
        float4 ev = lrelu4(add4(ssrc[csr_src[i]], sd));
        m.x = fmaxf(m.x, ev.x); m.y = fmaxf(m.y, ev.y);
        m.z = fmaxf(m.z, ev.z); m.w = fmaxf(m.w, ev.w);
    }
    for (int o = 32; o; o >>= 1) {
        m.x = fmaxf(m.x, __shfl_xor(m.x, o));
        m.y = fmaxf(m.y, __shfl_xor(m.y, o));
        m.z = fmaxf(m.z, __shfl_xor(m.z, o));
        m.w = fmaxf(m.w, __shfl_xor(m.w, o));
    }

    float4 den = make_float4(0.f, 0.f, 0.f, 0.f);
    for (int i = beg + lane; i < end; i += 64) {
        float4 ev = lrelu4(add4(ssrc[csr_src[i]], sd));
        den.x += __expf(ev.x - m.x); den.y += __expf(ev.y - m.y);
        den.z += __expf(ev.z - m.z); den.w += __expf(ev.w - m.w);
    }
    for (int o = 32; o; o >>= 1) {
        den.x += __shfl_xor(den.x, o);
        den.y += __shfl_xor(den.y, o);
        den.z += __shfl_xor(den.z, o);
        den.w += __shfl_xor(den.w, o);
    }
    float4 inv;
    inv.x = 1.f / den.x; inv.y = 1.f / den.y;
    inv.z = 1.f / den.z; inv.w = 1.f / den.w;

    const int head = lane >> 4;
    float acc[8] = {};
    for (int chunk = beg; chunk < end; chunk += 64) {
        const int n = min(64, end - chunk);
        if (lane < n) {
            int i = chunk + lane;
            float4 ev = lrelu4(add4(ssrc[csr_src[i]], sd));
            float4 a4;
            a4.x = __expf(ev.x - m.x) * inv.x;
            a4.y = __expf(ev.y - m.y) * inv.y;
            a4.z = __expf(ev.z - m.z) * inv.z;
            a4.w = __expf(ev.w - m.w) * inv.w;
            alds[w][lane][0] = a4.x; alds[w][lane][1] = a4.y;
            alds[w][lane][2] = a4.z; alds[w][lane][3] = a4.w;
            if (aout != nullptr) aout[csr_eid[i]] = a4;
        }
        for (int j = 0; j < n; ++j) {
            int s = csr_src[chunk + j];
            float a = alds[w][j][head];
            uint4 q = *(const uint4*)(hb + (size_t)s * 512 + lane * 8);
            acc[0] += a * __uint_as_float(q.x << 16);
            acc[1] += a * __uint_as_float(q.x & 0xFFFF0000u);
            acc[2] += a * __uint_as_float(q.y << 16);
            acc[3] += a * __uint_as_float(q.y & 0xFFFF0000u);
            acc[4] += a * __uint_as_float(q.z << 16);
            acc[5] += a * __uint_as_float(q.z & 0xFFFF0000u);
            acc[6] += a * __uint_as_float(q.w << 16);
            acc[7] += a * __uint_as_float(q.w & 0xFFFF0000u);
        }
    }

    if (concat) {
        float4* orow = (float4*)(out + (size_t)d * 512 + lane * 8);
        orow[0] = make_float4(acc[0], acc[1], acc[2], acc[3]);
        orow[1] = make_float4(acc[4], acc[5], acc[6], acc[7]);
    } else {
        // head-mean across lane groups {l, l^16, l^32, l^48}
#pragma unroll
        for (int k = 0; k < 8; k++) acc[k] += __shfl_xor(acc[k], 16);
#pragma unroll
        for (int k = 0; k < 8; k++) acc[k] += __shfl_xor(acc[k], 32);
        // fused: x = mean + b1; LayerNorm(128); lrelu; write bf16
        const int c0 = (lane & 15) * 8;
        float val[8];
        float s = 0.f;
#pragma unroll
        for (int k = 0; k < 8; k++) { val[k] = 0.25f * acc[k] + b1[c0 + k]; s += val[k]; }
#pragma unroll
        for (int o = 1; o <= 8; o <<= 1) s += __shfl_xor(s, o);
        float mu = s * (1.f / 128.f);
        float v = 0.f;
#pragma unroll
        for (int k = 0; k < 8; k++) { float dk = val[k] - mu; v += dk * dk; }
#pragma unroll
        for (int o = 1; o <= 8; o <<= 1) v += __shfl_xor(v, o);
        float r = rsqrtf(v * (1.f / 128.f) + 1e-5f);
        if (lane < 16) {
            unsigned int u[4];
#pragma unroll
            for (int k = 0; k < 4; k++) {
                float y0 = lrelu(gln[c0 + 2 * k]     * (val[2 * k]     - mu) * r + bln[c0 + 2 * k]);
                float y1 = lrelu(gln[c0 + 2 * k + 1] * (val[2 * k + 1] - mu) * r + bln[c0 + 2 * k + 1]);
                u[k] = (unsigned int)f2bf(y0) | ((unsigned int)f2bf(y1) << 16);
            }
            *(uint4*)&outb[(size_t)d * 128 + c0] = make_uint4(u[0], u[1], u[2], u[3]);
        }
    }
}

// pooled[g,c] += sum over nodes of lrelu(out2[n,c]+b2[c]); batch is sorted.
__global__ __launch_bounds__(512) void pool_k(const float* __restrict__ out2,
                                              const float* __restrict__ b2,
                                              const int* __restrict__ batch,
                                              float* __restrict__ pooled, int Nn) {
    int c = threadIdx.x;
    int n0 = blockIdx.x * 64, n1 = min(n0 + 64, Nn);
    if (n0 >= Nn) return;
    float bc = b2[c];
    int g = batch[n0];
    float acc = 0.f;
    for (int n = n0; n < n1; ++n) {
        int bg = batch[n];
        if (bg != g) { atomicAdd(&pooled[g * 512 + c], acc); acc = 0.f; g = bg; }
        float v = out2[(size_t)n * 512 + c] + bc;
        acc += lrelu(v);
    }
    atomicAdd(&pooled[g * 512 + c], acc);
}

// ---------------------------------------------------------------------------
// Whole MLP head in one kernel: one block per graph g (256 threads).
// count via binary search on sorted batch; lin0..lin3 staged through LDS.
// ---------------------------------------------------------------------------
__device__ __forceinline__ float block_sum(float v, volatile float* sbuf, int tid, int nw) {
    for (int o = 32; o; o >>= 1) v += __shfl_down(v, o);
    if ((tid & 63) == 0) sbuf[tid >> 6] = v;
    __syncthreads();
    if (tid == 0) { float r = 0.f; for (int i = 0; i < nw; i++) r += sbuf[i]; sbuf[0] = r; }
    __syncthreads();
    float r = sbuf[0];
    __syncthreads();
    return r;
}

__global__ __launch_bounds__(256) void mlp_head(const float* __restrict__ pooled,
                                                const int* __restrict__ batch, int Nn,
                                                const float* __restrict__ Wl0, const float* __restrict__ bl0,
                                                const float* __restrict__ Ws1, const float* __restrict__ bs1,
                                                const float* __restrict__ g1,  const float* __restrict__ bb1,
                                                const float* __restrict__ Ws2, const float* __restrict__ bs2,
                                                const float* __restrict__ g2,  const float* __restrict__ bb2,
                                                const float* __restrict__ Ws3, const float* __restrict__ bs3,
                                                float* __restrict__ probs) {
    __shared__ float z0[128], z1[256], z2[128];
    __shared__ float sbuf[8];
    const int g = blockIdx.x, t = threadIdx.x;

    // count (all threads compute the same; cheap)
    int lo = 0, hi = Nn;
    while (lo < hi) { int mid = (lo + hi) >> 1; if (batch[mid] < g) lo = mid + 1; else hi = mid; }
    int a = lo;
    lo = 0; hi = Nn;
    while (lo < hi) { int mid = (lo + hi) >> 1; if (batch[mid] < g + 1) lo = mid + 1; else hi = mid; }
    float inv = 1.f / fmaxf((float)(lo - a), 1.f);

    // lin0: z0 = pooled/cnt @ Wl0 + bl0
    if (t < 128) {
        float acc = 0.f;
        for (int k = 0; k < 512; k++) acc += pooled[g * 512 + k] * Wl0[k * 128 + t];
        z0[t] = acc * inv + bl0[t];
    }
    __syncthreads();

    // lin1 (256 out) + LN + relu
    {
        float acc = bs1[t];
        for (int k = 0; k < 128; k++) acc += z0[k] * Ws1[k * 256 + t];
        float mu = block_sum(acc, sbuf, t, 4) * (1.f / 256.f);
        float dd = acc - mu;
        float var = block_sum(dd * dd, sbuf, t, 4) * (1.f / 256.f);
        z1[t] = fmaxf(g1[t] * dd * rsqrtf(var + 1e-5f) + bb1[t], 0.f);
    }
    __syncthreads();

    // lin2 (128 out) + LN + relu (all 256 threads join reductions)
    {
        float acc = 0.f;
        if (t < 128) {
            acc = bs2[t];
            for (int k = 0; k < 256; k++) acc += z1[k] * Ws2[k * 128 + t];
        }
        float mu = block_sum(acc, sbuf, t, 4) * (1.f / 128.f);
        float dd = (t < 128) ? acc - mu : 0.f;
        float var = block_sum(dd * dd, sbuf, t, 4) * (1.f / 128.f);
        if (t < 128) z2[t] = fmaxf(g2[t] * dd * rsqrtf(var + 1e-5f) + bb2[t], 0.f);
    }
    __syncthreads();

    // lin3 + softmax
    if (t == 0) {
        float p0 = bs3[0], p1 = bs3[1];
        for (int k = 0; k < 128; k++) { p0 += z2[k] * Ws3[k * 2]; p1 += z2[k] * Ws3[k * 2 + 1]; }
        float mx = fmaxf(p0, p1);
        float e0 = __expf(p0 - mx), e1 = __expf(p1 - mx);
        float s = e0 + e1;
        probs[g * 2 + 0] = e0 / s;
        probs[g * 2 + 1] = e1 / s;
    }
}

// ---------------------------------------------------------------------------
extern "C" void kernel_launch(void* const* d_in, const int* in_sizes, int n_in,
                              void* d_out, int out_size, void* d_ws, size_t ws_size,
                              hipStream_t stream) {
    const float* x    = (const float*)d_in[0];
    const int*   ei   = (const int*)d_in[1];
    const int*   batch= (const int*)d_in[2];
    const float* W1   = (const float*)d_in[3];
    const float* as1  = (const float*)d_in[4];
    const float* ad1  = (const float*)d_in[5];
    const float* b1   = (const float*)d_in[6];
    const float* g_ln = (const float*)d_in[7];
    const float* b_ln = (const float*)d_in[8];
    const float* W2   = (const float*)d_in[9];
    const float* as2  = (const float*)d_in[10];
    const float* ad2  = (const float*)d_in[11];
    const float* b2   = (const float*)d_in[12];
    const float* Wl0  = (const float*)d_in[13];
    const float* bl0  = (const float*)d_in[14];
    const float* Ws1  = (const float*)d_in[15];
    const float* bs1  = (const float*)d_in[16];
    const float* g1   = (const float*)d_in[17];
    const float* bb1  = (const float*)d_in[18];
    const float* Ws2  = (const float*)d_in[19];
    const float* bs2  = (const float*)d_in[20];
    const float* g2   = (const float*)d_in[21];
    const float* bb2  = (const float*)d_in[22];
    const float* Ws3  = (const float*)d_in[23];
    const float* bs3  = (const float*)d_in[24];
    (void)n_in; (void)out_size; (void)ws_size;

    const int Nn = in_sizes[0] / 128;   // 30000
    const int E  = in_sizes[1] / 2;     // 480000
    const int ET = E + Nn;              // 510000
    const int G  = 64;

    // ---- workspace layout ----
    char* ws = (char*)d_ws;
    size_t off = 0;
    auto alloc = [&](size_t bytes) { void* p = ws + off; off += (bytes + 255) & ~(size_t)255; return p; };
    unsigned short* hb   = (unsigned short*)alloc((size_t)Nn * 512 * 2); // bf16 h
    unsigned short* xb   = (unsigned short*)alloc((size_t)Nn * 128 * 2); // bf16 x
    unsigned short* hlnb = (unsigned short*)alloc((size_t)Nn * 128 * 2); // bf16 LN(out1)
    unsigned short* Wbt1 = (unsigned short*)alloc((size_t)4 * 128 * 128 * 2);
    unsigned short* Wbt2 = (unsigned short*)alloc((size_t)4 * 128 * 128 * 2);
    float* out2   = (float*)alloc((size_t)Nn * 512 * 4);
    float* pooled = (float*)alloc((size_t)G * 512 * 4);
    float* ssrc   = (float*)alloc((size_t)Nn * 4 * 4);
    float* sdst   = (float*)alloc((size_t)Nn * 4 * 4);
    int*   deg    = (int*)alloc((size_t)Nn * 4);
    int*   rowptr = (int*)alloc((size_t)(Nn + 1) * 4);
    int*   cursor = (int*)alloc((size_t)Nn * 4);
    int*   csr_src= (int*)alloc((size_t)ET * 4);
    int*   csr_eid= (int*)alloc((size_t)ET * 4);

    float* probs = (float*)d_out;
    float* aout  = (float*)d_out + 128;   // alpha [ET,4]

    // ---- init ----
    hipMemsetAsync(deg, 0, (size_t)Nn * 4, stream);
    hipMemsetAsync(pooled, 0, (size_t)G * 512 * 4, stream);

    const int eblks = (ET + 255) / 256;
    dim3 ggrid((Nn + 63) / 64, 4);
    const int ablks = (Nn + 3) / 4;

    // ---- input conversions ----
    cvt_bf16_k<<<(Nn * 128 / 4 + 255) / 256, 256, 0, stream>>>(x, xb, Nn * 128 / 4);
    cvt_wt_k<<<dim3(64, 4, 2), 256, 0, stream>>>(W1, W2, Wbt1, Wbt2);

    // ---- CSR build ----
    hist_k<<<eblks, 256, 0, stream>>>(ei, E, ET, deg);
    scan_k<<<1, 1024, 0, stream>>>(deg, rowptr, cursor, Nn);
    fill_csr_k<<<eblks, 256, 0, stream>>>(ei, E, ET, cursor, csr_src, csr_eid);

    // ---- layer 1 ----
    gemm_mfma<<<ggrid, 256, 0, stream>>>(xb, Wbt1, hb, as1, ad1, ssrc, sdst, Nn);
    gat_agg<<<ablks, 256, 0, stream>>>(rowptr, csr_src, csr_eid,
                                       (const float4*)ssrc, (const float4*)sdst,
                                       hb, nullptr, hlnb, nullptr, b1, g_ln, b_ln, Nn, 0);

    // ---- layer 2 ----
    gemm_mfma<<<ggrid, 256, 0, stream>>>(hlnb, Wbt2, hb, as2, ad2, ssrc, sdst, Nn);
    gat_agg<<<ablks, 256, 0, stream>>>(rowptr, csr_src, csr_eid,
                                       (const float4*)ssrc, (const float4*)sdst,
                                       hb, out2, nullptr, (float4*)aout,
                                       nullptr, nullptr, nullptr, Nn, 1);

    // ---- pool + MLP head ----
    pool_k<<<(Nn + 63) / 64, 512, 0, stream>>>(out2, b2, batch, pooled, Nn);
    mlp_head<<<G, 256, 0, stream>>>(pooled, batch, Nn, Wl0, bl0, Ws1, bs1, g1, bb1,
                                    Ws2, bs2, g2, bb2, Ws3, bs3, probs);
}